// Round 1
// baseline (1036.563 us; speedup 1.0000x reference)
//
#include <hip/hip_runtime.h>
#include <cstdint>
#include <cmath>

#define D_MODEL 256
#define NH 8
#define HD 32
#define NLVL 4
#define NPT 4
#define LTOT 13294
#define BATCH 4
#define BTOT (BATCH * LTOT)   // 53176
#define F1 512                 // vp(256) | attn-logits(128) | box(128)

// levels: (100,100),(50,50),(25,25),(13,13); offsets 0,10000,12500,13125
__device__ __forceinline__ void level_of(int l, int& lv, int& hw, int& Wl, int& HWl, int& loff) {
    if (l < 10000)      { lv = 0; loff = 0;     Wl = 100; HWl = 10000; }
    else if (l < 12500) { lv = 1; loff = 10000; Wl = 50;  HWl = 2500;  }
    else if (l < 13125) { lv = 2; loff = 12500; Wl = 25;  HWl = 625;   }
    else                { lv = 3; loff = 13125; Wl = 13;  HWl = 169;   }
    hw = l - loff;
}

// ---------------------------------------------------------------- pack weights
// Wt  (256 x 512): Wt[c*512+f] = {Wv[f][c] | Wattn[f-256][c] | Wbox[f-384][c]}
// Wot (256 x 256): Wot[c*256+f] = Wo[f][c]
__global__ void pack_weights(const float* __restrict__ Wv, const float* __restrict__ Wattn,
                             const float* __restrict__ Wbox, const float* __restrict__ Wo,
                             float* __restrict__ Wt, float* __restrict__ Wot) {
    int idx = blockIdx.x * 256 + threadIdx.x;
    if (idx < 256 * 512) {
        int c = idx >> 9, f = idx & 511;
        float w;
        if (f < 256)      w = Wv[f * 256 + c];
        else if (f < 384) w = Wattn[(f - 256) * 256 + c];
        else              w = Wbox[(f - 384) * 256 + c];
        Wt[idx] = w;
    } else {
        int j = idx - 256 * 512;
        if (j < 256 * 256) {
            int c = j >> 8, f = j & 255;
            Wot[j] = Wo[f * 256 + c];
        }
    }
}

// ---------------------------------------------------------------- GEMM1
// P[r, 0:256]  = value[r] @ Wv^T + bv
// P[r,256:384] = (value+pos)[r] @ Wattn^T + battn
// P[r,384:512] = (value+pos)[r] @ Wbox^T + bbox
__global__ __launch_bounds__(256) void gemm1_kernel(
    const float* __restrict__ v0, const float* __restrict__ v1,
    const float* __restrict__ v2, const float* __restrict__ v3,
    const float* __restrict__ p0, const float* __restrict__ p1,
    const float* __restrict__ p2, const float* __restrict__ p3,
    const float* __restrict__ Wt,
    const float* __restrict__ bv, const float* __restrict__ battn, const float* __restrict__ bbox,
    float* __restrict__ P) {
    const int BM = 128, BN = 64, BK = 64;
    __shared__ float As[BK * BM];
    __shared__ float Bs[BK * BN];
    int t = threadIdx.x;
    int n0 = blockIdx.x * BN;
    int r0 = blockIdx.y * BM;
    bool useQ = (n0 >= 256);

    // A-load assignment: fixed row per thread
    int ia = t & 127;
    int ka = t >> 7;              // 0..1
    int r  = r0 + ia;
    int rb = r < BTOT ? r : BTOT - 1;
    int b  = rb / LTOT, l = rb % LTOT;
    int lv, hw, Wl, HWl, loff;
    level_of(l, lv, hw, Wl, HWl, loff);
    const float* vb; const float* pb;
    switch (lv) {
        case 0:  vb = v0; pb = p0; break;
        case 1:  vb = v1; pb = p1; break;
        case 2:  vb = v2; pb = p2; break;
        default: vb = v3; pb = p3; break;
    }
    size_t base = (size_t)b * D_MODEL * (size_t)HWl + (size_t)hw;
    vb += base; pb += base;

    // B-load assignment
    int jb = t & 63, kb = t >> 6;  // kb 0..3
    int tx = t & 15, ty = t >> 4;

    float acc[8][4] = {};
    for (int kk = 0; kk < 256; kk += BK) {
        __syncthreads();
        // A tile: As[k][i]
        #pragma unroll 8
        for (int it = 0; it < 32; ++it) {
            int k = ka + it * 2;
            float a = vb[(size_t)(kk + k) * HWl];
            if (useQ) a += pb[(size_t)(kk + k) * HWl];
            As[k * BM + ia] = a;
        }
        // B tile: Bs[k][j]
        #pragma unroll 8
        for (int it = 0; it < 16; ++it) {
            int k = kb + it * 4;
            Bs[k * BN + jb] = Wt[(size_t)(kk + k) * F1 + n0 + jb];
        }
        __syncthreads();
        #pragma unroll
        for (int k = 0; k < BK; ++k) {
            float4 a0 = *(const float4*)&As[k * BM + ty * 8];
            float4 a1 = *(const float4*)&As[k * BM + ty * 8 + 4];
            float4 bb = *(const float4*)&Bs[k * BN + tx * 4];
            float av[8] = {a0.x, a0.y, a0.z, a0.w, a1.x, a1.y, a1.z, a1.w};
            float bw[4] = {bb.x, bb.y, bb.z, bb.w};
            #pragma unroll
            for (int ii = 0; ii < 8; ++ii)
                #pragma unroll
                for (int jj = 0; jj < 4; ++jj)
                    acc[ii][jj] = fmaf(av[ii], bw[jj], acc[ii][jj]);
        }
    }
    // epilogue
    int f0 = n0 + tx * 4;
    const float* bptr = (f0 < 256) ? &bv[f0] : ((f0 < 384) ? &battn[f0 - 256] : &bbox[f0 - 384]);
    float4 bias = *(const float4*)bptr;
    #pragma unroll
    for (int ii = 0; ii < 8; ++ii) {
        int rr = r0 + ty * 8 + ii;
        if (rr < BTOT) {
            float4 o;
            o.x = acc[ii][0] + bias.x; o.y = acc[ii][1] + bias.y;
            o.z = acc[ii][2] + bias.z; o.w = acc[ii][3] + bias.w;
            *(float4*)&P[(size_t)rr * F1 + f0] = o;
        }
    }
}

// ---------------------------------------------------------------- sampler
// per group (b,l,m), 32 lanes (d): softmax(16 logits), box->grid, bilinear
// gather from vp (inside P), weighted sum -> att[(b*L+l)*256 + m*32 + d]
__global__ __launch_bounds__(256) void sampler_kernel(const float* __restrict__ P,
                                                      float* __restrict__ att) {
    int gid = blockIdx.x * 256 + threadIdx.x;
    int d   = gid & 31;
    int grp = gid >> 5;                 // (b*L + l)*8 + m
    if (grp >= BTOT * NH) return;
    int m = grp & 7;
    int r = grp >> 3;                   // b*L + l
    int l = r % LTOT;
    int rb0 = r - l;                    // b*L

    int lv, hw, Wl, HWl, loff;
    level_of(l, lv, hw, Wl, HWl, loff);
    int x, y;
    switch (lv) {
        case 0:  y = hw / 100; x = hw - y * 100; break;
        case 1:  y = hw / 50;  x = hw - y * 50;  break;
        case 2:  y = hw / 25;  x = hw - y * 25;  break;
        default: y = hw / 13;  x = hw - y * 13;  break;
    }
    float fW    = (float)Wl;
    float denom = (float)((double)Wl + 1e-6);    // matches (H + EPS) cast to f32
    float cx = ((float)x + 0.5f) / denom;
    float cy = ((float)y + 0.5f) / denom;
    float rsw = 4.0f / fW;                       // REF_SIZE/W (= /H, square levels)

    const float* Prow = P + (size_t)r * F1;
    // softmax over 16
    float lg[16];
    #pragma unroll
    for (int i = 0; i < 16; ++i) lg[i] = Prow[256 + m * 16 + i];
    float mx = lg[0];
    #pragma unroll
    for (int i = 1; i < 16; ++i) mx = fmaxf(mx, lg[i]);
    float s = 0.f;
    #pragma unroll
    for (int i = 0; i < 16; ++i) { lg[i] = expf(lg[i] - mx); s += lg[i]; }
    float inv = 1.0f / s;

    const int   Ws2[4]   = {100, 50, 25, 13};
    const int   offs2[4] = {0, 10000, 12500, 13125};

    float acc = 0.f;
    #pragma unroll
    for (int lp = 0; lp < NLVL; ++lp) {
        int W2 = Ws2[lp];
        float fW2 = (float)W2;
        float o0 = Prow[384 + m * 16 + lp * 4 + 0];
        float o1 = Prow[384 + m * 16 + lp * 4 + 1];
        float o2 = Prow[384 + m * 16 + lp * 4 + 2];
        float o3 = Prow[384 + m * 16 + lp * 4 + 3];
        float bcx = cx + o0 * 0.125f * rsw;
        float bcy = cy + o1 * 0.125f * rsw;
        float bsx = fmaxf(fmaf(o2 * 0.125f, rsw, rsw), 0.f);
        float bsy = fmaxf(fmaf(o3 * 0.125f, rsw, rsw), 0.f);
        const float* vbase = P + ((size_t)(rb0 + offs2[lp])) * F1 + m * 32 + d;
        #pragma unroll
        for (int p = 0; p < NPT; ++p) {
            float kx = (p & 1)  ? 0.25f : -0.25f;
            float ky = (p >> 1) ? 0.25f : -0.25f;
            float gx = bcx + kx * bsx;
            float gy = bcy + ky * bsy;
            float xs = gx * fW2 - 0.5f;
            float ys = gy * fW2 - 0.5f;
            float x0f = floorf(xs), y0f = floorf(ys);
            float lx = xs - x0f, ly = ys - y0f;
            int x0 = (int)x0f, y0 = (int)y0f;
            float aw = lg[lp * 4 + p] * inv;
            // 4 corners
            #pragma unroll
            for (int cny = 0; cny < 2; ++cny) {
                #pragma unroll
                for (int cnx = 0; cnx < 2; ++cnx) {
                    int xi = x0 + cnx, yi = y0 + cny;
                    bool valid = (xi >= 0) & (xi < W2) & (yi >= 0) & (yi < W2);
                    if (valid) {
                        float wx = cnx ? lx : (1.f - lx);
                        float wy = cny ? ly : (1.f - ly);
                        float g = vbase[(size_t)(yi * W2 + xi) * F1];
                        acc = fmaf(aw * wx * wy, g, acc);
                    }
                }
            }
        }
    }
    att[(size_t)grp * 32 + d] = acc;
}

// ---------------------------------------------------------------- GEMM2
// out[r, f] = att[r, :] @ Wot[:, f] + bo[f]
__global__ __launch_bounds__(256) void gemm2_kernel(const float* __restrict__ A,
                                                    const float* __restrict__ Wot,
                                                    const float* __restrict__ bo,
                                                    float* __restrict__ out) {
    const int BM = 128, BN = 64, BK = 64, LDA = 132;  // pad to break transpose-write conflict
    __shared__ float As[BK * LDA];
    __shared__ float Bs[BK * BN];
    int t = threadIdx.x;
    int n0 = blockIdx.x * BN;
    int r0 = blockIdx.y * BM;
    int ca = t & 63, ia0 = t >> 6;   // 4 rows per pass
    int jb = t & 63, kb = t >> 6;
    int tx = t & 15, ty = t >> 4;

    float acc[8][4] = {};
    for (int kk = 0; kk < 256; kk += BK) {
        __syncthreads();
        #pragma unroll 8
        for (int it = 0; it < 32; ++it) {
            int i  = ia0 + it * 4;
            int rr = r0 + i; rr = rr < BTOT ? rr : BTOT - 1;
            As[ca * LDA + i] = A[(size_t)rr * 256 + kk + ca];
        }
        #pragma unroll 8
        for (int it = 0; it < 16; ++it) {
            int k = kb + it * 4;
            Bs[k * BN + jb] = Wot[(size_t)(kk + k) * 256 + n0 + jb];
        }
        __syncthreads();
        #pragma unroll
        for (int k = 0; k < BK; ++k) {
            float4 a0 = *(const float4*)&As[k * LDA + ty * 8];
            float4 a1 = *(const float4*)&As[k * LDA + ty * 8 + 4];
            float4 bb = *(const float4*)&Bs[k * BN + tx * 4];
            float av[8] = {a0.x, a0.y, a0.z, a0.w, a1.x, a1.y, a1.z, a1.w};
            float bw[4] = {bb.x, bb.y, bb.z, bb.w};
            #pragma unroll
            for (int ii = 0; ii < 8; ++ii)
                #pragma unroll
                for (int jj = 0; jj < 4; ++jj)
                    acc[ii][jj] = fmaf(av[ii], bw[jj], acc[ii][jj]);
        }
    }
    float4 bias = *(const float4*)&bo[n0 + tx * 4];
    #pragma unroll
    for (int ii = 0; ii < 8; ++ii) {
        int rr = r0 + ty * 8 + ii;
        if (rr < BTOT) {
            float4 o;
            o.x = acc[ii][0] + bias.x; o.y = acc[ii][1] + bias.y;
            o.z = acc[ii][2] + bias.z; o.w = acc[ii][3] + bias.w;
            *(float4*)&out[(size_t)rr * 256 + n0 + tx * 4] = o;
        }
    }
}

// ---------------------------------------------------------------- launch
extern "C" void kernel_launch(void* const* d_in, const int* in_sizes, int n_in,
                              void* d_out, int out_size, void* d_ws, size_t ws_size,
                              hipStream_t stream) {
    // dict order: value0,pos0,value1,pos1,value2,pos2,value3,pos3,
    //             Wv,bv,Wo,bo,Wbox,bbox,Wattn,battn
    const float* v0 = (const float*)d_in[0];
    const float* p0 = (const float*)d_in[1];
    const float* v1 = (const float*)d_in[2];
    const float* p1 = (const float*)d_in[3];
    const float* v2 = (const float*)d_in[4];
    const float* p2 = (const float*)d_in[5];
    const float* v3 = (const float*)d_in[6];
    const float* p3 = (const float*)d_in[7];
    const float* Wv    = (const float*)d_in[8];
    const float* bv    = (const float*)d_in[9];
    const float* Wo    = (const float*)d_in[10];
    const float* bo    = (const float*)d_in[11];
    const float* Wbox  = (const float*)d_in[12];
    const float* bbox  = (const float*)d_in[13];
    const float* Wattn = (const float*)d_in[14];
    const float* battn = (const float*)d_in[15];
    float* out = (float*)d_out;

    char* ws = (char*)d_ws;
    float* Wt  = (float*)ws;                                   // 512 KB
    float* Wot = (float*)(ws + 512 * 1024);                    // 256 KB
    float* P   = (float*)(ws + 1024 * 1024);                   // BTOT*512*4 = 108.9 MB
    float* att = (float*)(ws + 1024 * 1024 + (size_t)BTOT * F1 * 4);  // BTOT*256*4 = 54.5 MB

    pack_weights<<<dim3(768), dim3(256), 0, stream>>>(Wv, Wattn, Wbox, Wo, Wt, Wot);

    dim3 g1(F1 / 64, (BTOT + 127) / 128);
    gemm1_kernel<<<g1, dim3(256), 0, stream>>>(v0, v1, v2, v3, p0, p1, p2, p3,
                                               Wt, bv, battn, bbox, P);

    int sblocks = (BTOT * NH * 32 + 255) / 256;
    sampler_kernel<<<dim3(sblocks), dim3(256), 0, stream>>>(P, att);

    dim3 g2(256 / 64, (BTOT + 127) / 128);
    gemm2_kernel<<<g2, dim3(256), 0, stream>>>(att, Wot, bo, out);
}

// Round 3
// 655.847 us; speedup vs baseline: 1.5805x; 1.5805x over previous
//
#include <hip/hip_runtime.h>
#include <cstdint>
#include <cmath>

#define D_MODEL 256
#define NH 8
#define HD 32
#define NLVL 4
#define NPT 4
#define LTOT 13294
#define BATCH 4
#define BTOT (BATCH * LTOT)   // 53176
#define F1 512                 // vp(256) | attn-logits(128) | box(128)

// levels: (100,100),(50,50),(25,25),(13,13); offsets 0,10000,12500,13125
__device__ __forceinline__ void level_of(int l, int& lv, int& hw, int& Wl, int& HWl, int& loff) {
    if (l < 10000)      { lv = 0; loff = 0;     Wl = 100; HWl = 10000; }
    else if (l < 12500) { lv = 1; loff = 10000; Wl = 50;  HWl = 2500;  }
    else if (l < 13125) { lv = 2; loff = 12500; Wl = 25;  HWl = 625;   }
    else                { lv = 3; loff = 13125; Wl = 13;  HWl = 169;   }
    hw = l - loff;
}

// ---------------------------------------------------------------- pack weights
__global__ void pack_weights(const float* __restrict__ Wv, const float* __restrict__ Wattn,
                             const float* __restrict__ Wbox, const float* __restrict__ Wo,
                             float* __restrict__ Wt, float* __restrict__ Wot) {
    int idx = blockIdx.x * 256 + threadIdx.x;
    if (idx < 256 * 512) {
        int c = idx >> 9, f = idx & 511;
        float w;
        if (f < 256)      w = Wv[f * 256 + c];
        else if (f < 384) w = Wattn[(f - 256) * 256 + c];
        else              w = Wbox[(f - 384) * 256 + c];
        Wt[idx] = w;
    } else {
        int j = idx - 256 * 512;
        if (j < 256 * 256) {
            int c = j >> 8, f = j & 255;
            Wot[j] = Wo[f * 256 + c];
        }
    }
}

// ---------------------------------------------------------------- GEMM1
__global__ __launch_bounds__(256) void gemm1_kernel(
    const float* __restrict__ v0, const float* __restrict__ v1,
    const float* __restrict__ v2, const float* __restrict__ v3,
    const float* __restrict__ p0, const float* __restrict__ p1,
    const float* __restrict__ p2, const float* __restrict__ p3,
    const float* __restrict__ Wt,
    const float* __restrict__ bv, const float* __restrict__ battn, const float* __restrict__ bbox,
    float* __restrict__ P) {
    const int BM = 128, BN = 64, BK = 64;
    __shared__ float As[BK * BM];
    __shared__ float Bs[BK * BN];
    int t = threadIdx.x;
    int n0 = blockIdx.x * BN;
    int r0 = blockIdx.y * BM;
    bool useQ = (n0 >= 256);

    int ia = t & 127;
    int ka = t >> 7;
    int r  = r0 + ia;
    int rb = r < BTOT ? r : BTOT - 1;
    int b  = rb / LTOT, l = rb % LTOT;
    int lv, hw, Wl, HWl, loff;
    level_of(l, lv, hw, Wl, HWl, loff);
    const float* vb; const float* pb;
    switch (lv) {
        case 0:  vb = v0; pb = p0; break;
        case 1:  vb = v1; pb = p1; break;
        case 2:  vb = v2; pb = p2; break;
        default: vb = v3; pb = p3; break;
    }
    size_t base = (size_t)b * D_MODEL * (size_t)HWl + (size_t)hw;
    vb += base; pb += base;

    int jb = t & 63, kb = t >> 6;
    int tx = t & 15, ty = t >> 4;

    float acc[8][4] = {};
    for (int kk = 0; kk < 256; kk += BK) {
        __syncthreads();
        #pragma unroll 8
        for (int it = 0; it < 32; ++it) {
            int k = ka + it * 2;
            float a = vb[(size_t)(kk + k) * HWl];
            if (useQ) a += pb[(size_t)(kk + k) * HWl];
            As[k * BM + ia] = a;
        }
        #pragma unroll 8
        for (int it = 0; it < 16; ++it) {
            int k = kb + it * 4;
            Bs[k * BN + jb] = Wt[(size_t)(kk + k) * F1 + n0 + jb];
        }
        __syncthreads();
        #pragma unroll
        for (int k = 0; k < BK; ++k) {
            float4 a0 = *(const float4*)&As[k * BM + ty * 8];
            float4 a1 = *(const float4*)&As[k * BM + ty * 8 + 4];
            float4 bb = *(const float4*)&Bs[k * BN + tx * 4];
            float av[8] = {a0.x, a0.y, a0.z, a0.w, a1.x, a1.y, a1.z, a1.w};
            float bw[4] = {bb.x, bb.y, bb.z, bb.w};
            #pragma unroll
            for (int ii = 0; ii < 8; ++ii)
                #pragma unroll
                for (int jj = 0; jj < 4; ++jj)
                    acc[ii][jj] = fmaf(av[ii], bw[jj], acc[ii][jj]);
        }
    }
    int f0 = n0 + tx * 4;
    const float* bptr = (f0 < 256) ? &bv[f0] : ((f0 < 384) ? &battn[f0 - 256] : &bbox[f0 - 384]);
    float4 bias = *(const float4*)bptr;
    #pragma unroll
    for (int ii = 0; ii < 8; ++ii) {
        int rr = r0 + ty * 8 + ii;
        if (rr < BTOT) {
            float4 o;
            o.x = acc[ii][0] + bias.x; o.y = acc[ii][1] + bias.y;
            o.z = acc[ii][2] + bias.z; o.w = acc[ii][3] + bias.w;
            *(float4*)&P[(size_t)rr * F1 + f0] = o;
        }
    }
}

// ---------------------------------------------------------------- sampler v2
// Block = 256 threads handles 8 groups (grp = r*8+m); grid = BTOT*NH/8 blocks.
// Phase 1 (128 threads = 8 grp x 16 pt): softmax via 16-lane shfl reduce,
//   box->grid, premultiplied bilinear corner weights + 4 clamped flat indices -> LDS.
// Phase 2 (256 threads = 8 grp x 32 d): 16 pts x (LDS broadcast read + 4 gathers + 4 fma).
__global__ __launch_bounds__(256) void sampler_kernel(const float* __restrict__ P,
                                                      float* __restrict__ att) {
    __shared__ float sw[8][16][8];   // [g][p][w00,w01,w10,w11, idx00,idx01,idx10,idx11(int)]
    const int Ws2[4]   = {100, 50, 25, 13};
    const int offs2[4] = {0, 10000, 12500, 13125};
    int t = threadIdx.x;
    int blk = blockIdx.x;            // BTOT*NH/8 = 53176 blocks, 8 groups each (exact)

    if (t < 128) {
        int g = t >> 4, p = t & 15;
        int grp = blk * 8 + g;
        int m = grp & 7;
        int r = grp >> 3;            // b*L + l
        int l = r % LTOT;
        int rb0 = r - l;

        int lv, hw, Wl, HWl, loff;
        level_of(l, lv, hw, Wl, HWl, loff);
        int x, y;
        switch (lv) {
            case 0:  y = hw / 100; x = hw - y * 100; break;
            case 1:  y = hw / 50;  x = hw - y * 50;  break;
            case 2:  y = hw / 25;  x = hw - y * 25;  break;
            default: y = hw / 13;  x = hw - y * 13;  break;
        }
        float denom = (float)((double)Wl + 1e-6);
        float cx = ((float)x + 0.5f) / denom;
        float cy = ((float)y + 0.5f) / denom;
        float rsw = 4.0f / (float)Wl;

        const float* Prow = P + (size_t)r * F1;
        // softmax over the 16 points of this group (one logit per thread)
        float lg = Prow[256 + m * 16 + p];
        float mx = lg;
        #pragma unroll
        for (int off = 8; off >= 1; off >>= 1)
            mx = fmaxf(mx, __shfl_xor(mx, off, 16));
        float e = __expf(lg - mx);
        float s = e;
        #pragma unroll
        for (int off = 8; off >= 1; off >>= 1)
            s += __shfl_xor(s, off, 16);
        float aw = e / s;

        int lp = p >> 2, pp = p & 3;
        int W2 = Ws2[lp];
        float fW2 = (float)W2;
        float o0 = Prow[384 + m * 16 + lp * 4 + 0];
        float o1 = Prow[384 + m * 16 + lp * 4 + 1];
        float o2 = Prow[384 + m * 16 + lp * 4 + 2];
        float o3 = Prow[384 + m * 16 + lp * 4 + 3];
        float bcx = cx + o0 * 0.125f * rsw;
        float bcy = cy + o1 * 0.125f * rsw;
        float bsx = fmaxf(fmaf(o2 * 0.125f, rsw, rsw), 0.f);
        float bsy = fmaxf(fmaf(o3 * 0.125f, rsw, rsw), 0.f);
        float kx = (pp & 1)  ? 0.25f : -0.25f;
        float ky = (pp >> 1) ? 0.25f : -0.25f;
        float xs = fmaf(bcx + kx * bsx, fW2, -0.5f);
        float ys = fmaf(bcy + ky * bsy, fW2, -0.5f);
        float x0f = floorf(xs), y0f = floorf(ys);
        float lx = xs - x0f, ly = ys - y0f;
        int x0 = (int)x0f, y0 = (int)y0f;
        int x1 = x0 + 1, y1 = y0 + 1;
        bool vx0 = (x0 >= 0) & (x0 < W2), vx1 = (x1 >= 0) & (x1 < W2);
        bool vy0 = (y0 >= 0) & (y0 < W2), vy1 = (y1 >= 0) & (y1 < W2);
        int x0c = min(max(x0, 0), W2 - 1), x1c = min(max(x1, 0), W2 - 1);
        int y0c = min(max(y0, 0), W2 - 1), y1c = min(max(y1, 0), W2 - 1);
        float w00 = (vx0 & vy0) ? aw * (1.f - lx) * (1.f - ly) : 0.f;
        float w01 = (vx1 & vy0) ? aw * lx * (1.f - ly) : 0.f;
        float w10 = (vx0 & vy1) ? aw * (1.f - lx) * ly : 0.f;
        float w11 = (vx1 & vy1) ? aw * lx * ly : 0.f;
        int rowb = rb0 + offs2[lp];
        int col  = m * 32;
        int i00 = (rowb + y0c * W2 + x0c) * F1 + col;
        int i01 = (rowb + y0c * W2 + x1c) * F1 + col;
        int i10 = (rowb + y1c * W2 + x0c) * F1 + col;
        int i11 = (rowb + y1c * W2 + x1c) * F1 + col;
        sw[g][p][0] = w00; sw[g][p][1] = w01; sw[g][p][2] = w10; sw[g][p][3] = w11;
        sw[g][p][4] = __int_as_float(i00); sw[g][p][5] = __int_as_float(i01);
        sw[g][p][6] = __int_as_float(i10); sw[g][p][7] = __int_as_float(i11);
    }
    __syncthreads();

    int g = t >> 5, d = t & 31;
    float acc = 0.f;
    #pragma unroll
    for (int p = 0; p < 16; ++p) {
        float4 w  = *(const float4*)&sw[g][p][0];
        float4 fi = *(const float4*)&sw[g][p][4];
        int i00 = __float_as_int(fi.x), i01 = __float_as_int(fi.y);
        int i10 = __float_as_int(fi.z), i11 = __float_as_int(fi.w);
        acc = fmaf(w.x, P[i00 + d], acc);
        acc = fmaf(w.y, P[i01 + d], acc);
        acc = fmaf(w.z, P[i10 + d], acc);
        acc = fmaf(w.w, P[i11 + d], acc);
    }
    att[(size_t)(blk * 8 + g) * 32 + d] = acc;
}

// ---------------------------------------------------------------- GEMM2
__global__ __launch_bounds__(256) void gemm2_kernel(const float* __restrict__ A,
                                                    const float* __restrict__ Wot,
                                                    const float* __restrict__ bo,
                                                    float* __restrict__ out) {
    const int BM = 128, BN = 64, BK = 64, LDA = 132;
    __shared__ float As[BK * LDA];
    __shared__ float Bs[BK * BN];
    int t = threadIdx.x;
    int n0 = blockIdx.x * BN;
    int r0 = blockIdx.y * BM;
    int ca = t & 63, ia0 = t >> 6;
    int jb = t & 63, kb = t >> 6;
    int tx = t & 15, ty = t >> 4;

    float acc[8][4] = {};
    for (int kk = 0; kk < 256; kk += BK) {
        __syncthreads();
        #pragma unroll 8
        for (int it = 0; it < 32; ++it) {
            int i  = ia0 + it * 4;
            int rr = r0 + i; rr = rr < BTOT ? rr : BTOT - 1;
            As[ca * LDA + i] = A[(size_t)rr * 256 + kk + ca];
        }
        #pragma unroll 8
        for (int it = 0; it < 16; ++it) {
            int k = kb + it * 4;
            Bs[k * BN + jb] = Wot[(size_t)(kk + k) * 256 + n0 + jb];
        }
        __syncthreads();
        #pragma unroll
        for (int k = 0; k < BK; ++k) {
            float4 a0 = *(const float4*)&As[k * LDA + ty * 8];
            float4 a1 = *(const float4*)&As[k * LDA + ty * 8 + 4];
            float4 bb = *(const float4*)&Bs[k * BN + tx * 4];
            float av[8] = {a0.x, a0.y, a0.z, a0.w, a1.x, a1.y, a1.z, a1.w};
            float bw[4] = {bb.x, bb.y, bb.z, bb.w};
            #pragma unroll
            for (int ii = 0; ii < 8; ++ii)
                #pragma unroll
                for (int jj = 0; jj < 4; ++jj)
                    acc[ii][jj] = fmaf(av[ii], bw[jj], acc[ii][jj]);
        }
    }
    float4 bias = *(const float4*)&bo[n0 + tx * 4];
    #pragma unroll
    for (int ii = 0; ii < 8; ++ii) {
        int rr = r0 + ty * 8 + ii;
        if (rr < BTOT) {
            float4 o;
            o.x = acc[ii][0] + bias.x; o.y = acc[ii][1] + bias.y;
            o.z = acc[ii][2] + bias.z; o.w = acc[ii][3] + bias.w;
            *(float4*)&out[(size_t)rr * 256 + n0 + tx * 4] = o;
        }
    }
}

// ---------------------------------------------------------------- launch
extern "C" void kernel_launch(void* const* d_in, const int* in_sizes, int n_in,
                              void* d_out, int out_size, void* d_ws, size_t ws_size,
                              hipStream_t stream) {
    const float* v0 = (const float*)d_in[0];
    const float* p0 = (const float*)d_in[1];
    const float* v1 = (const float*)d_in[2];
    const float* p1 = (const float*)d_in[3];
    const float* v2 = (const float*)d_in[4];
    const float* p2 = (const float*)d_in[5];
    const float* v3 = (const float*)d_in[6];
    const float* p3 = (const float*)d_in[7];
    const float* Wv    = (const float*)d_in[8];
    const float* bv    = (const float*)d_in[9];
    const float* Wo    = (const float*)d_in[10];
    const float* bo    = (const float*)d_in[11];
    const float* Wbox  = (const float*)d_in[12];
    const float* bbox  = (const float*)d_in[13];
    const float* Wattn = (const float*)d_in[14];
    const float* battn = (const float*)d_in[15];
    float* out = (float*)d_out;

    char* ws = (char*)d_ws;
    float* Wt  = (float*)ws;
    float* Wot = (float*)(ws + 512 * 1024);
    float* P   = (float*)(ws + 1024 * 1024);
    float* att = (float*)(ws + 1024 * 1024 + (size_t)BTOT * F1 * 4);

    pack_weights<<<dim3(768), dim3(256), 0, stream>>>(Wv, Wattn, Wbox, Wo, Wt, Wot);

    dim3 g1(F1 / 64, (BTOT + 127) / 128);
    gemm1_kernel<<<g1, dim3(256), 0, stream>>>(v0, v1, v2, v3, p0, p1, p2, p3,
                                               Wt, bv, battn, bbox, P);

    // 8 groups per block over BTOT*NH groups total
    sampler_kernel<<<dim3((BTOT * NH) / 8), dim3(256), 0, stream>>>(P, att);

    dim3 g2(256 / 64, (BTOT + 127) / 128);
    gemm2_kernel<<<g2, dim3(256), 0, stream>>>(att, Wot, bo, out);
}

// Round 4
// 492.294 us; speedup vs baseline: 2.1056x; 1.3322x over previous
//
#include <hip/hip_runtime.h>
#include <cstdint>
#include <cmath>

#define D_MODEL 256
#define NH 8
#define NLVL 4
#define LTOT 13294
#define BATCH 4
#define BTOT (BATCH * LTOT)   // 53176

typedef __attribute__((ext_vector_type(8))) short bf8;
typedef __attribute__((ext_vector_type(4))) float f4;

__device__ __forceinline__ unsigned short f2bf(float x) {
    unsigned u = __float_as_uint(x);
    u += 0x7fffu + ((u >> 16) & 1u);      // round-to-nearest-even
    return (unsigned short)(u >> 16);
}
__device__ __forceinline__ float bf2f(unsigned short h) {
    return __uint_as_float(((unsigned)h) << 16);
}
// XOR swizzle of 16B octet slot s within a 64B row i (2-way max on 64-lane access)
__device__ __forceinline__ int swzf(int i, int s) { return s ^ ((i >> 1) & 3); }

// levels: (100,100),(50,50),(25,25),(13,13); offsets 0,10000,12500,13125
__device__ __forceinline__ void level_of(int l, int& lv, int& hw, int& Wl, int& HWl, int& loff) {
    if (l < 10000)      { lv = 0; loff = 0;     Wl = 100; HWl = 10000; }
    else if (l < 12500) { lv = 1; loff = 10000; Wl = 50;  HWl = 2500;  }
    else if (l < 13125) { lv = 2; loff = 12500; Wl = 25;  HWl = 625;   }
    else                { lv = 3; loff = 13125; Wl = 13;  HWl = 169;   }
    hw = l - loff;
}

// ---------------------------------------------------------------- pack weights
// Splits weights into bf16 hi/lo planes laid out EXACTLY as the GEMM LDS tiles:
// per (nb,kb) tile: col j (0..127) row of 32 k as 4 octets, octet s stored at
// slot swzf(j,s). GEMM staging then is a linear coalesced copy.
__global__ __launch_bounds__(256) void pack_weights(
    const float* __restrict__ Wv, const float* __restrict__ Wattn,
    const float* __restrict__ Wbox, const float* __restrict__ Wo,
    unsigned short* __restrict__ W1hi, unsigned short* __restrict__ W1lo,
    unsigned short* __restrict__ Wohi, unsigned short* __restrict__ Wolo) {
    int tid = blockIdx.x * 256 + threadIdx.x;
    const float* src;
    unsigned short *dh, *dl;
    int nb, kb, j, s;
    if (tid < 16384) {                       // GEMM1 B: 4 nb x 8 kb x 128 j x 4 s
        nb = tid >> 12; kb = (tid >> 9) & 7; j = (tid >> 2) & 127; s = tid & 3;
        int f = nb * 128 + j, c0 = kb * 32 + s * 8;
        if (f < 256)      src = Wv + (size_t)f * 256 + c0;
        else if (f < 384) src = Wattn + (size_t)(f - 256) * 256 + c0;
        else              src = Wbox + (size_t)(f - 384) * 256 + c0;
        dh = W1hi; dl = W1lo;
    } else if (tid < 24576) {                // GEMM2 B: 2 nb x 8 kb x 128 j x 4 s
        int t2 = tid - 16384;
        nb = t2 >> 12; kb = (t2 >> 9) & 7; j = (t2 >> 2) & 127; s = t2 & 3;
        int f = nb * 128 + j, c0 = kb * 32 + s * 8;
        src = Wo + (size_t)f * 256 + c0;
        dh = Wohi; dl = Wolo;
    } else return;
    int base = (((nb * 8 + kb) * 128 + j) * 4 + swzf(j, s)) * 8;
    #pragma unroll
    for (int e = 0; e < 8; ++e) {
        float x = src[e];
        unsigned short h = f2bf(x);
        dh[base + e] = h;
        dl[base + e] = f2bf(x - bf2f(h));
    }
}

// ---------------------------------------------------------------- GEMM1 (MFMA)
// C[r, 0:256] = value @ Wv^T + bv        -> VPb (bf16)
// C[r, 256:512] = (value+pos) @ [Wattn;Wbox]^T + b -> LB (f32)
// 128x128 tile, BK=32, 4 waves (2x2), each wave 4x4 of 16x16x32 MFMA,
// split-bf16 3-product accumulation.
__global__ __launch_bounds__(256) void gemm1_mfma(
    const float* __restrict__ v0, const float* __restrict__ v1,
    const float* __restrict__ v2, const float* __restrict__ v3,
    const float* __restrict__ p0, const float* __restrict__ p1,
    const float* __restrict__ p2, const float* __restrict__ p3,
    const unsigned short* __restrict__ W1hi, const unsigned short* __restrict__ W1lo,
    const float* __restrict__ bv, const float* __restrict__ battn, const float* __restrict__ bbox,
    unsigned short* __restrict__ VPb, float* __restrict__ LB) {
    __shared__ __align__(16) unsigned short Ahi[4096], Alo[4096], Bhi[4096], Blo[4096];
    int t = threadIdx.x;
    int nb = blockIdx.x;                 // 0..3 (128-col blocks of F1=512)
    int r0 = blockIdx.y * 128;
    bool useQ = (nb >= 2);

    // A-staging assignment: thread owns row ia, k-half hh
    int ia = t & 127, hh = t >> 7;
    int rb = r0 + ia; if (rb >= BTOT) rb = BTOT - 1;
    int b = rb / LTOT, l = rb % LTOT;
    int lv, hw, Wl, HWl, loff;
    level_of(l, lv, hw, Wl, HWl, loff);
    const float* vb; const float* pb;
    switch (lv) { case 0: vb = v0; pb = p0; break; case 1: vb = v1; pb = p1; break;
                  case 2: vb = v2; pb = p2; break; default: vb = v3; pb = p3; break; }
    size_t abase = (size_t)b * D_MODEL * (size_t)HWl + (size_t)hw;
    vb += abase; pb += abase;

    int wv = t >> 6, ln = t & 63;
    int wr = wv >> 1, wc = wv & 1;       // wave sub-tile (64x64)
    int row_l = ln & 15, oct = ln >> 4;  // MFMA lane mapping

    f4 acc[4][4];
    #pragma unroll
    for (int i = 0; i < 4; ++i)
        #pragma unroll
        for (int j = 0; j < 4; ++j) acc[i][j] = (f4){0.f, 0.f, 0.f, 0.f};

    const float4* __restrict__ bh4 = (const float4*)(W1hi + (size_t)nb * 32768);
    const float4* __restrict__ bl4 = (const float4*)(W1lo + (size_t)nb * 32768);

    for (int kb = 0; kb < 8; ++kb) {
        __syncthreads();
        // ---- B stage: linear coalesced copy of prepacked tile (8KB/plane)
        {
            int o = kb * 512;
            ((float4*)Bhi)[t]       = bh4[o + t];
            ((float4*)Bhi)[t + 256] = bh4[o + t + 256];
            ((float4*)Blo)[t]       = bl4[o + t];
            ((float4*)Blo)[t + 256] = bl4[o + t + 256];
        }
        // ---- A stage: 16 strided f32 loads, split to bf16 hi/lo, swizzled b128 writes
        {
            int kk = kb * 32 + hh * 16;
            const float* vp0 = vb + (size_t)kk * HWl;
            const float* pp0 = pb + (size_t)kk * HWl;
            float vals[16];
            #pragma unroll
            for (int j = 0; j < 16; ++j) {
                float a = vp0[(size_t)j * HWl];
                if (useQ) a += pp0[(size_t)j * HWl];
                vals[j] = a;
            }
            #pragma unroll
            for (int o = 0; o < 2; ++o) {
                int s = hh * 2 + o;
                unsigned hv[4], lw[4];
                #pragma unroll
                for (int q = 0; q < 4; ++q) {
                    float x0 = vals[o * 8 + q * 2], x1 = vals[o * 8 + q * 2 + 1];
                    unsigned short h0 = f2bf(x0), h1 = f2bf(x1);
                    unsigned short l0 = f2bf(x0 - bf2f(h0)), l1 = f2bf(x1 - bf2f(h1));
                    hv[q] = ((unsigned)h1 << 16) | h0;
                    lw[q] = ((unsigned)l1 << 16) | l0;
                }
                int epos = ia * 32 + swzf(ia, s) * 8;
                *(uint4*)(&Ahi[epos]) = make_uint4(hv[0], hv[1], hv[2], hv[3]);
                *(uint4*)(&Alo[epos]) = make_uint4(lw[0], lw[1], lw[2], lw[3]);
            }
        }
        __syncthreads();
        // ---- compute: 16 frag reads + 48 MFMA
        bf8 ah[4], al[4], bh[4], blx[4];
        #pragma unroll
        for (int x = 0; x < 4; ++x) {
            int ri = wr * 64 + x * 16 + row_l;
            int ci = wc * 64 + x * 16 + row_l;
            ah[x]  = *(const bf8*)(&Ahi[ri * 32 + swzf(ri, oct) * 8]);
            al[x]  = *(const bf8*)(&Alo[ri * 32 + swzf(ri, oct) * 8]);
            bh[x]  = *(const bf8*)(&Bhi[ci * 32 + swzf(ci, oct) * 8]);
            blx[x] = *(const bf8*)(&Blo[ci * 32 + swzf(ci, oct) * 8]);
        }
        #pragma unroll
        for (int mi = 0; mi < 4; ++mi)
            #pragma unroll
            for (int ni = 0; ni < 4; ++ni) {
                f4 c = acc[mi][ni];
                c = __builtin_amdgcn_mfma_f32_16x16x32_bf16(ah[mi], bh[ni], c, 0, 0, 0);
                c = __builtin_amdgcn_mfma_f32_16x16x32_bf16(ah[mi], blx[ni], c, 0, 0, 0);
                c = __builtin_amdgcn_mfma_f32_16x16x32_bf16(al[mi], bh[ni], c, 0, 0, 0);
                acc[mi][ni] = c;
            }
    }
    // ---- epilogue: C layout col=lane&15, row=(lane>>4)*4+v
    #pragma unroll
    for (int ni = 0; ni < 4; ++ni) {
        int col = wc * 64 + ni * 16 + row_l;
        float bias;
        if (nb == 0) bias = bv[col];
        else if (nb == 1) bias = bv[128 + col];
        else if (nb == 2) bias = battn[col];
        else bias = bbox[col];
        #pragma unroll
        for (int mi = 0; mi < 4; ++mi) {
            #pragma unroll
            for (int v = 0; v < 4; ++v) {
                int rr = r0 + wr * 64 + mi * 16 + oct * 4 + v;
                if (rr < BTOT) {
                    float val = acc[mi][ni][v] + bias;
                    if (nb < 2) VPb[(size_t)rr * 256 + nb * 128 + col] = f2bf(val);
                    else        LB[(size_t)rr * 256 + (nb - 2) * 128 + col] = val;
                }
            }
        }
    }
}

// ---------------------------------------------------------------- sampler v3
// Phase 1 (128 thr = 8 grp x 16 pt): softmax + box->grid -> LDS (weights+indices).
// Phase 2 (256 thr = 8 grp x 32 d): gathers from bf16 vp, writes att split
// bf16 hi/lo pre-swizzled for GEMM2's LDS layout.
__global__ __launch_bounds__(256) void sampler_kernel(const unsigned short* __restrict__ VPb,
                                                      const float* __restrict__ LB,
                                                      unsigned short* __restrict__ att_hi,
                                                      unsigned short* __restrict__ att_lo) {
    __shared__ float sw[8][16][8];   // [g][p][w00,w01,w10,w11, i00,i01,i10,i11]
    const int Ws2[4]   = {100, 50, 25, 13};
    const int offs2[4] = {0, 10000, 12500, 13125};
    int t = threadIdx.x;
    int blk = blockIdx.x;            // BTOT*NH/8 blocks

    if (t < 128) {
        int g = t >> 4, p = t & 15;
        int grp = blk * 8 + g;
        int m = grp & 7;
        int r = grp >> 3;
        int l = r % LTOT;
        int rb0 = r - l;

        int lv, hw, Wl, HWl, loff;
        level_of(l, lv, hw, Wl, HWl, loff);
        int x, y;
        switch (lv) {
            case 0:  y = hw / 100; x = hw - y * 100; break;
            case 1:  y = hw / 50;  x = hw - y * 50;  break;
            case 2:  y = hw / 25;  x = hw - y * 25;  break;
            default: y = hw / 13;  x = hw - y * 13;  break;
        }
        float denom = (float)((double)Wl + 1e-6);
        float cx = ((float)x + 0.5f) / denom;
        float cy = ((float)y + 0.5f) / denom;
        float rsw = 4.0f / (float)Wl;

        const float* Lrow = LB + (size_t)r * 256;
        float lg = Lrow[m * 16 + p];
        float mx = lg;
        #pragma unroll
        for (int off = 8; off >= 1; off >>= 1)
            mx = fmaxf(mx, __shfl_xor(mx, off, 16));
        float e = __expf(lg - mx);
        float ssum = e;
        #pragma unroll
        for (int off = 8; off >= 1; off >>= 1)
            ssum += __shfl_xor(ssum, off, 16);
        float aw = e / ssum;

        int lp = p >> 2, pp = p & 3;
        int W2 = Ws2[lp];
        float fW2 = (float)W2;
        float o0 = Lrow[128 + m * 16 + lp * 4 + 0];
        float o1 = Lrow[128 + m * 16 + lp * 4 + 1];
        float o2 = Lrow[128 + m * 16 + lp * 4 + 2];
        float o3 = Lrow[128 + m * 16 + lp * 4 + 3];
        float bcx = cx + o0 * 0.125f * rsw;
        float bcy = cy + o1 * 0.125f * rsw;
        float bsx = fmaxf(fmaf(o2 * 0.125f, rsw, rsw), 0.f);
        float bsy = fmaxf(fmaf(o3 * 0.125f, rsw, rsw), 0.f);
        float kx = (pp & 1)  ? 0.25f : -0.25f;
        float ky = (pp >> 1) ? 0.25f : -0.25f;
        float xs = fmaf(bcx + kx * bsx, fW2, -0.5f);
        float ys = fmaf(bcy + ky * bsy, fW2, -0.5f);
        float x0f = floorf(xs), y0f = floorf(ys);
        float lx = xs - x0f, ly = ys - y0f;
        int x0 = (int)x0f, y0 = (int)y0f;
        int x1 = x0 + 1, y1 = y0 + 1;
        bool vx0 = (x0 >= 0) & (x0 < W2), vx1 = (x1 >= 0) & (x1 < W2);
        bool vy0 = (y0 >= 0) & (y0 < W2), vy1 = (y1 >= 0) & (y1 < W2);
        int x0c = min(max(x0, 0), W2 - 1), x1c = min(max(x1, 0), W2 - 1);
        int y0c = min(max(y0, 0), W2 - 1), y1c = min(max(y1, 0), W2 - 1);
        float w00 = (vx0 & vy0) ? aw * (1.f - lx) * (1.f - ly) : 0.f;
        float w01 = (vx1 & vy0) ? aw * lx * (1.f - ly) : 0.f;
        float w10 = (vx0 & vy1) ? aw * (1.f - lx) * ly : 0.f;
        float w11 = (vx1 & vy1) ? aw * lx * ly : 0.f;
        int rowb = rb0 + offs2[lp];
        int col  = m * 32;
        int i00 = (rowb + y0c * W2 + x0c) * 256 + col;
        int i01 = (rowb + y0c * W2 + x1c) * 256 + col;
        int i10 = (rowb + y1c * W2 + x0c) * 256 + col;
        int i11 = (rowb + y1c * W2 + x1c) * 256 + col;
        sw[g][p][0] = w00; sw[g][p][1] = w01; sw[g][p][2] = w10; sw[g][p][3] = w11;
        sw[g][p][4] = __int_as_float(i00); sw[g][p][5] = __int_as_float(i01);
        sw[g][p][6] = __int_as_float(i10); sw[g][p][7] = __int_as_float(i11);
    }
    __syncthreads();

    int g = t >> 5, d = t & 31;
    float acc = 0.f;
    #pragma unroll
    for (int p = 0; p < 16; ++p) {
        float4 w  = *(const float4*)&sw[g][p][0];
        float4 fi = *(const float4*)&sw[g][p][4];
        int i00 = __float_as_int(fi.x), i01 = __float_as_int(fi.y);
        int i10 = __float_as_int(fi.z), i11 = __float_as_int(fi.w);
        acc = fmaf(w.x, bf2f(VPb[i00 + d]), acc);
        acc = fmaf(w.y, bf2f(VPb[i01 + d]), acc);
        acc = fmaf(w.z, bf2f(VPb[i10 + d]), acc);
        acc = fmaf(w.w, bf2f(VPb[i11 + d]), acc);
    }
    int grp = blk * 8 + g;
    int m2 = grp & 7, r2 = grp >> 3;
    unsigned short h = f2bf(acc);
    unsigned short lo = f2bf(acc - bf2f(h));
    // pre-swizzled for GEMM2: within the 32-k window, octet (d>>3) at slot swzf(r2, d>>3)
    size_t base = (size_t)r2 * 256 + m2 * 32 + (((d >> 3) ^ ((r2 >> 1) & 3)) << 3) + (d & 7);
    att_hi[base] = h;
    att_lo[base] = lo;
}

// ---------------------------------------------------------------- GEMM2 (MFMA)
// out = att @ Wo^T + bo. A and B both prepacked (swizzled) -> pure copy staging.
__global__ __launch_bounds__(256) void gemm2_mfma(
    const unsigned short* __restrict__ Ahi_g, const unsigned short* __restrict__ Alo_g,
    const unsigned short* __restrict__ Wohi, const unsigned short* __restrict__ Wolo,
    const float* __restrict__ bo, float* __restrict__ out) {
    __shared__ __align__(16) unsigned short Ahi[4096], Alo[4096], Bhi[4096], Blo[4096];
    int t = threadIdx.x;
    int nb = blockIdx.x;                 // 0..1
    int r0 = blockIdx.y * 128;
    int wv = t >> 6, ln = t & 63;
    int wr = wv >> 1, wc = wv & 1;
    int row_l = ln & 15, oct = ln >> 4;

    int i0 = t >> 2, q0 = t & 3;
    int ra  = min(r0 + i0, BTOT - 1);
    int rbq = min(r0 + 64 + i0, BTOT - 1);

    const float4* __restrict__ bh4 = (const float4*)(Wohi + (size_t)nb * 32768);
    const float4* __restrict__ bl4 = (const float4*)(Wolo + (size_t)nb * 32768);

    f4 acc[4][4];
    #pragma unroll
    for (int i = 0; i < 4; ++i)
        #pragma unroll
        for (int j = 0; j < 4; ++j) acc[i][j] = (f4){0.f, 0.f, 0.f, 0.f};

    for (int kb = 0; kb < 8; ++kb) {
        __syncthreads();
        {
            int o = kb * 512;
            ((float4*)Bhi)[t]       = bh4[o + t];
            ((float4*)Bhi)[t + 256] = bh4[o + t + 256];
            ((float4*)Blo)[t]       = bl4[o + t];
            ((float4*)Blo)[t + 256] = bl4[o + t + 256];
            size_t s0 = (size_t)ra  * 256 + kb * 32 + q0 * 8;
            size_t s1 = (size_t)rbq * 256 + kb * 32 + q0 * 8;
            ((float4*)Ahi)[t]       = *(const float4*)(Ahi_g + s0);
            ((float4*)Ahi)[t + 256] = *(const float4*)(Ahi_g + s1);
            ((float4*)Alo)[t]       = *(const float4*)(Alo_g + s0);
            ((float4*)Alo)[t + 256] = *(const float4*)(Alo_g + s1);
        }
        __syncthreads();
        bf8 ah[4], al[4], bh[4], blx[4];
        #pragma unroll
        for (int x = 0; x < 4; ++x) {
            int ri = wr * 64 + x * 16 + row_l;
            int ci = wc * 64 + x * 16 + row_l;
            ah[x]  = *(const bf8*)(&Ahi[ri * 32 + swzf(ri, oct) * 8]);
            al[x]  = *(const bf8*)(&Alo[ri * 32 + swzf(ri, oct) * 8]);
            bh[x]  = *(const bf8*)(&Bhi[ci * 32 + swzf(ci, oct) * 8]);
            blx[x] = *(const bf8*)(&Blo[ci * 32 + swzf(ci, oct) * 8]);
        }
        #pragma unroll
        for (int mi = 0; mi < 4; ++mi)
            #pragma unroll
            for (int ni = 0; ni < 4; ++ni) {
                f4 c = acc[mi][ni];
                c = __builtin_amdgcn_mfma_f32_16x16x32_bf16(ah[mi], bh[ni], c, 0, 0, 0);
                c = __builtin_amdgcn_mfma_f32_16x16x32_bf16(ah[mi], blx[ni], c, 0, 0, 0);
                c = __builtin_amdgcn_mfma_f32_16x16x32_bf16(al[mi], bh[ni], c, 0, 0, 0);
                acc[mi][ni] = c;
            }
    }
    #pragma unroll
    for (int ni = 0; ni < 4; ++ni) {
        int col = wc * 64 + ni * 16 + row_l;
        float bias = bo[nb * 128 + col];
        #pragma unroll
        for (int mi = 0; mi < 4; ++mi) {
            #pragma unroll
            for (int v = 0; v < 4; ++v) {
                int rr = r0 + wr * 64 + mi * 16 + oct * 4 + v;
                if (rr < BTOT)
                    out[(size_t)rr * 256 + nb * 128 + col] = acc[mi][ni][v] + bias;
            }
        }
    }
}

// ---------------------------------------------------------------- launch
extern "C" void kernel_launch(void* const* d_in, const int* in_sizes, int n_in,
                              void* d_out, int out_size, void* d_ws, size_t ws_size,
                              hipStream_t stream) {
    const float* v0 = (const float*)d_in[0];
    const float* p0 = (const float*)d_in[1];
    const float* v1 = (const float*)d_in[2];
    const float* p1 = (const float*)d_in[3];
    const float* v2 = (const float*)d_in[4];
    const float* p2 = (const float*)d_in[5];
    const float* v3 = (const float*)d_in[6];
    const float* p3 = (const float*)d_in[7];
    const float* Wv    = (const float*)d_in[8];
    const float* bv    = (const float*)d_in[9];
    const float* Wo    = (const float*)d_in[10];
    const float* bo    = (const float*)d_in[11];
    const float* Wbox  = (const float*)d_in[12];
    const float* bbox  = (const float*)d_in[13];
    const float* Wattn = (const float*)d_in[14];
    const float* battn = (const float*)d_in[15];
    float* out = (float*)d_out;

    char* ws = (char*)d_ws;
    unsigned short* W1hi = (unsigned short*)(ws);                       // 256KB
    unsigned short* W1lo = (unsigned short*)(ws + 262144);              // 256KB
    unsigned short* Wohi = (unsigned short*)(ws + 524288);              // 128KB
    unsigned short* Wolo = (unsigned short*)(ws + 655360);              // 128KB
    unsigned short* VPb  = (unsigned short*)(ws + 1048576);             // 27.2MB bf16 vp
    float*          LB   = (float*)(ws + 1048576 + 27226112);           // 54.5MB f32 logits|box
    unsigned short* atth = (unsigned short*)(ws + 1048576 + 27226112 + 54452224);            // 27.2MB
    unsigned short* attl = (unsigned short*)(ws + 1048576 + 27226112 + 54452224 + 27226112); // 27.2MB

    pack_weights<<<dim3(96), dim3(256), 0, stream>>>(Wv, Wattn, Wbox, Wo,
                                                     W1hi, W1lo, Wohi, Wolo);

    gemm1_mfma<<<dim3(4, (BTOT + 127) / 128), dim3(256), 0, stream>>>(
        v0, v1, v2, v3, p0, p1, p2, p3, W1hi, W1lo, bv, battn, bbox, VPb, LB);

    sampler_kernel<<<dim3((BTOT * NH) / 8), dim3(256), 0, stream>>>(VPb, LB, atth, attl);

    gemm2_mfma<<<dim3(2, (BTOT + 127) / 128), dim3(256), 0, stream>>>(
        atth, attl, Wohi, Wolo, bo, out);
}

// Round 5
// 302.551 us; speedup vs baseline: 3.4261x; 1.6271x over previous
//
#include <hip/hip_runtime.h>
#include <cstdint>
#include <cmath>

#define D_MODEL 256
#define NH 8
#define NLVL 4
#define LTOT 13294
#define BATCH 4
#define BTOT (BATCH * LTOT)   // 53176
#define RPAD 53248             // 416 * 128 padded rows

typedef __attribute__((ext_vector_type(8))) short bf8;
typedef __attribute__((ext_vector_type(4))) float f4;

__device__ __forceinline__ unsigned short f2bf(float x) {
    unsigned u = __float_as_uint(x);
    u += 0x7fffu + ((u >> 16) & 1u);      // round-to-nearest-even
    return (unsigned short)(u >> 16);
}
__device__ __forceinline__ float bf2f(unsigned short h) {
    return __uint_as_float(((unsigned)h) << 16);
}
// chunk-slot swizzle: slot s of row i holds k-octet s ^ ((i>>1)&3)
__device__ __forceinline__ int swzf(int i, int s) { return s ^ ((i >> 1) & 3); }

// levels: (100,100),(50,50),(25,25),(13,13); offsets 0,10000,12500,13125
__device__ __forceinline__ void level_of(int l, int& lv, int& hw, int& Wl, int& HWl, int& loff) {
    if (l < 10000)      { lv = 0; loff = 0;     Wl = 100; HWl = 10000; }
    else if (l < 12500) { lv = 1; loff = 10000; Wl = 50;  HWl = 2500;  }
    else if (l < 13125) { lv = 2; loff = 12500; Wl = 25;  HWl = 625;   }
    else                { lv = 3; loff = 13125; Wl = 13;  HWl = 169;   }
    hw = l - loff;
}

// ---------------------------------------------------------------- pack weights
// B prepacked per (nb,kb) tile: col j row of 32 k as 4 octets, octet s at slot
// swzf(j,s). GEMM B staging is then a linear global_load_lds copy.
__global__ __launch_bounds__(256) void pack_weights(
    const float* __restrict__ Wv, const float* __restrict__ Wattn,
    const float* __restrict__ Wbox, const float* __restrict__ Wo,
    unsigned short* __restrict__ W1hi, unsigned short* __restrict__ W1lo,
    unsigned short* __restrict__ Wohi, unsigned short* __restrict__ Wolo) {
    int tid = blockIdx.x * 256 + threadIdx.x;
    const float* src;
    unsigned short *dh, *dl;
    int nb, kb, j, s;
    if (tid < 16384) {                       // GEMM1 B: 4 nb x 8 kb x 128 j x 4 s
        nb = tid >> 12; kb = (tid >> 9) & 7; j = (tid >> 2) & 127; s = tid & 3;
        int f = nb * 128 + j, c0 = kb * 32 + s * 8;
        if (f < 256)      src = Wv + (size_t)f * 256 + c0;
        else if (f < 384) src = Wattn + (size_t)(f - 256) * 256 + c0;
        else              src = Wbox + (size_t)(f - 384) * 256 + c0;
        dh = W1hi; dl = W1lo;
    } else if (tid < 24576) {                // GEMM2 B: 2 nb x 8 kb x 128 j x 4 s
        int t2 = tid - 16384;
        nb = t2 >> 12; kb = (t2 >> 9) & 7; j = (t2 >> 2) & 127; s = t2 & 3;
        int f = nb * 128 + j, c0 = kb * 32 + s * 8;
        src = Wo + (size_t)f * 256 + c0;
        dh = Wohi; dl = Wolo;
    } else return;
    int base = (((nb * 8 + kb) * 128 + j) * 4 + swzf(j, s)) * 8;
    #pragma unroll
    for (int e = 0; e < 8; ++e) {
        float x = src[e];
        unsigned short h = f2bf(x);
        dh[base + e] = h;
        dl[base + e] = f2bf(x - bf2f(h));
    }
}

// ---------------------------------------------------------------- convert A
// Transpose value / (value+pos) from (B, C, HW) to row-major bf16-hi panels in
// the GEMM chunk layout: G[r*256 + kb*32 + slot*8 + e], slot holds octet
// swz-mapped k. Block = 64 rows x 256 c, processed in 2 c-halves via LDS.
__global__ __launch_bounds__(256) void convert_A(
    const float* __restrict__ v0, const float* __restrict__ v1,
    const float* __restrict__ v2, const float* __restrict__ v3,
    const float* __restrict__ p0, const float* __restrict__ p1,
    const float* __restrict__ p2, const float* __restrict__ p3,
    unsigned short* __restrict__ Gv, unsigned short* __restrict__ Gq) {
    __shared__ unsigned short HV[64][130];
    __shared__ unsigned short HQ[64][130];
    int t = threadIdx.x;
    int w = t >> 6, lane = t & 63;
    int r0 = blockIdx.x * 64;

    int r = r0 + lane; if (r >= BTOT) r = BTOT - 1;
    int b = r / LTOT, l = r % LTOT;
    int lv, hw, Wl, HWl, loff;
    level_of(l, lv, hw, Wl, HWl, loff);
    const float *vb, *pb;
    switch (lv) { case 0: vb = v0; pb = p0; break; case 1: vb = v1; pb = p1; break;
                  case 2: vb = v2; pb = p2; break; default: vb = v3; pb = p3; break; }
    size_t base = (size_t)b * D_MODEL * (size_t)HWl + (size_t)hw;
    vb += base; pb += base;

    int kb2 = (lane >> 2) & 3, slot = lane & 3;
    for (int h = 0; h < 2; ++h) {
        // read phase: c_local = i*4 + w, row = lane (coalesced across lanes)
        #pragma unroll 4
        for (int i = 0; i < 32; ++i) {
            int cl = i * 4 + w;
            int c = h * 128 + cl;
            float av = vb[(size_t)c * HWl];
            float aq = av + pb[(size_t)c * HWl];
            HV[lane][cl] = f2bf(av);
            HQ[lane][cl] = f2bf(aq);
        }
        __syncthreads();
        // write phase: 8 iters; 16 lanes cover (kb2,slot)=256B per row, 4 rows/instr
        #pragma unroll
        for (int j = 0; j < 8; ++j) {
            int plane = j >> 2;
            int rl = (j & 3) * 16 + w * 4 + (lane >> 4);
            int oct = slot ^ ((rl >> 1) & 3);
            const unsigned* s32 = (const unsigned*)(plane ? &HQ[rl][kb2 * 32 + oct * 8]
                                                          : &HV[rl][kb2 * 32 + oct * 8]);
            uint4 vst = make_uint4(s32[0], s32[1], s32[2], s32[3]);
            unsigned short* dst = (plane ? Gq : Gv)
                + (size_t)(r0 + rl) * 256 + (h * 4 + kb2) * 32 + slot * 8;
            *(uint4*)dst = vst;
        }
        __syncthreads();
    }
}

// ---------------------------------------------------------------- GEMM1 (MFMA)
// C[:,0:256] = value @ Wv^T + bv -> VPb (bf16); C[:,256:512] = q @ [Wattn;Wbox]^T -> LB (f32)
// A = prepacked bf16-hi panel; staging all global_load_lds width-16.
// 2-product split (ah*bh + ah*bl).
__global__ __launch_bounds__(256) void gemm1_mfma(
    const unsigned short* __restrict__ Gv, const unsigned short* __restrict__ Gq,
    const unsigned short* __restrict__ W1hi, const unsigned short* __restrict__ W1lo,
    const float* __restrict__ bv, const float* __restrict__ battn, const float* __restrict__ bbox,
    unsigned short* __restrict__ VPb, float* __restrict__ LB) {
    __shared__ __align__(16) unsigned short Ah[4096], Bh[4096], Bl[4096];
    int t = threadIdx.x;
    int nb = blockIdx.x;                 // 0..3
    int r0 = blockIdx.y * 128;
    const unsigned short* Asrc = (nb < 2) ? Gv : Gq;
    int w = t >> 6, lane = t & 63;
    int wr = w >> 1, wc = w & 1;
    int row_l = lane & 15, oct = lane >> 4;

    const unsigned short* Bbh = W1hi + (size_t)nb * 32768;
    const unsigned short* Bbl = W1lo + (size_t)nb * 32768;

    f4 acc[4][4];
    #pragma unroll
    for (int i = 0; i < 4; ++i)
        #pragma unroll
        for (int j = 0; j < 4; ++j) acc[i][j] = (f4){0.f, 0.f, 0.f, 0.f};

    int c0 = w * 64 + lane, c1 = c0 + 256;
    for (int kb = 0; kb < 8; ++kb) {
        __syncthreads();
        {
            const unsigned short* a0 = Asrc + (size_t)(r0 + (c0 >> 2)) * 256 + kb * 32 + (c0 & 3) * 8;
            const unsigned short* a1 = Asrc + (size_t)(r0 + (c1 >> 2)) * 256 + kb * 32 + (c1 & 3) * 8;
            __builtin_amdgcn_global_load_lds(a0, &Ah[w * 512], 16, 0, 0);
            __builtin_amdgcn_global_load_lds(a1, &Ah[2048 + w * 512], 16, 0, 0);
            const unsigned short* b0 = Bbh + kb * 4096 + c0 * 8;
            const unsigned short* b1 = Bbh + kb * 4096 + c1 * 8;
            __builtin_amdgcn_global_load_lds(b0, &Bh[w * 512], 16, 0, 0);
            __builtin_amdgcn_global_load_lds(b1, &Bh[2048 + w * 512], 16, 0, 0);
            const unsigned short* b2 = Bbl + kb * 4096 + c0 * 8;
            const unsigned short* b3 = Bbl + kb * 4096 + c1 * 8;
            __builtin_amdgcn_global_load_lds(b2, &Bl[w * 512], 16, 0, 0);
            __builtin_amdgcn_global_load_lds(b3, &Bl[2048 + w * 512], 16, 0, 0);
        }
        __syncthreads();
        bf8 a[4], bh[4], bl[4];
        #pragma unroll
        for (int x = 0; x < 4; ++x) {
            int ri = wr * 64 + x * 16 + row_l;
            int ci = wc * 64 + x * 16 + row_l;
            a[x]  = *(const bf8*)(&Ah[ri * 32 + swzf(ri, oct) * 8]);
            bh[x] = *(const bf8*)(&Bh[ci * 32 + swzf(ci, oct) * 8]);
            bl[x] = *(const bf8*)(&Bl[ci * 32 + swzf(ci, oct) * 8]);
        }
        #pragma unroll
        for (int mi = 0; mi < 4; ++mi)
            #pragma unroll
            for (int ni = 0; ni < 4; ++ni) {
                f4 c = acc[mi][ni];
                c = __builtin_amdgcn_mfma_f32_16x16x32_bf16(a[mi], bh[ni], c, 0, 0, 0);
                c = __builtin_amdgcn_mfma_f32_16x16x32_bf16(a[mi], bl[ni], c, 0, 0, 0);
                acc[mi][ni] = c;
            }
    }
    // epilogue: C layout col=lane&15, row=(lane>>4)*4+v
    #pragma unroll
    for (int ni = 0; ni < 4; ++ni) {
        int col = wc * 64 + ni * 16 + row_l;
        float bias;
        if (nb == 0) bias = bv[col];
        else if (nb == 1) bias = bv[128 + col];
        else if (nb == 2) bias = battn[col];
        else bias = bbox[col];
        #pragma unroll
        for (int mi = 0; mi < 4; ++mi) {
            #pragma unroll
            for (int v = 0; v < 4; ++v) {
                int rr = r0 + wr * 64 + mi * 16 + oct * 4 + v;
                if (rr < BTOT) {
                    float val = acc[mi][ni][v] + bias;
                    if (nb < 2) VPb[(size_t)rr * 256 + nb * 128 + col] = f2bf(val);
                    else        LB[(size_t)rr * 256 + (nb - 2) * 128 + col] = val;
                }
            }
        }
    }
}

// ---------------------------------------------------------------- sampler
__global__ __launch_bounds__(256) void sampler_kernel(const unsigned short* __restrict__ VPb,
                                                      const float* __restrict__ LB,
                                                      unsigned short* __restrict__ att_hi,
                                                      unsigned short* __restrict__ att_lo) {
    __shared__ float sw[8][16][8];   // [g][p][w00,w01,w10,w11, i00,i01,i10,i11]
    const int Ws2[4]   = {100, 50, 25, 13};
    const int offs2[4] = {0, 10000, 12500, 13125};
    int t = threadIdx.x;
    int blk = blockIdx.x;            // BTOT*NH/8 blocks

    if (t < 128) {
        int g = t >> 4, p = t & 15;
        int grp = blk * 8 + g;
        int m = grp & 7;
        int r = grp >> 3;
        int l = r % LTOT;
        int rb0 = r - l;

        int lv, hw, Wl, HWl, loff;
        level_of(l, lv, hw, Wl, HWl, loff);
        int x, y;
        switch (lv) {
            case 0:  y = hw / 100; x = hw - y * 100; break;
            case 1:  y = hw / 50;  x = hw - y * 50;  break;
            case 2:  y = hw / 25;  x = hw - y * 25;  break;
            default: y = hw / 13;  x = hw - y * 13;  break;
        }
        float denom = (float)((double)Wl + 1e-6);
        float cx = ((float)x + 0.5f) / denom;
        float cy = ((float)y + 0.5f) / denom;
        float rsw = 4.0f / (float)Wl;

        const float* Lrow = LB + (size_t)r * 256;
        float lg = Lrow[m * 16 + p];
        float mx = lg;
        #pragma unroll
        for (int off = 8; off >= 1; off >>= 1)
            mx = fmaxf(mx, __shfl_xor(mx, off, 16));
        float e = __expf(lg - mx);
        float ssum = e;
        #pragma unroll
        for (int off = 8; off >= 1; off >>= 1)
            ssum += __shfl_xor(ssum, off, 16);
        float aw = e / ssum;

        int lp = p >> 2, pp = p & 3;
        int W2 = Ws2[lp];
        float fW2 = (float)W2;
        float o0 = Lrow[128 + m * 16 + lp * 4 + 0];
        float o1 = Lrow[128 + m * 16 + lp * 4 + 1];
        float o2 = Lrow[128 + m * 16 + lp * 4 + 2];
        float o3 = Lrow[128 + m * 16 + lp * 4 + 3];
        float bcx = cx + o0 * 0.125f * rsw;
        float bcy = cy + o1 * 0.125f * rsw;
        float bsx = fmaxf(fmaf(o2 * 0.125f, rsw, rsw), 0.f);
        float bsy = fmaxf(fmaf(o3 * 0.125f, rsw, rsw), 0.f);
        float kx = (pp & 1)  ? 0.25f : -0.25f;
        float ky = (pp >> 1) ? 0.25f : -0.25f;
        float xs = fmaf(bcx + kx * bsx, fW2, -0.5f);
        float ys = fmaf(bcy + ky * bsy, fW2, -0.5f);
        float x0f = floorf(xs), y0f = floorf(ys);
        float lx = xs - x0f, ly = ys - y0f;
        int x0 = (int)x0f, y0 = (int)y0f;
        int x1 = x0 + 1, y1 = y0 + 1;
        bool vx0 = (x0 >= 0) & (x0 < W2), vx1 = (x1 >= 0) & (x1 < W2);
        bool vy0 = (y0 >= 0) & (y0 < W2), vy1 = (y1 >= 0) & (y1 < W2);
        int x0c = min(max(x0, 0), W2 - 1), x1c = min(max(x1, 0), W2 - 1);
        int y0c = min(max(y0, 0), W2 - 1), y1c = min(max(y1, 0), W2 - 1);
        float w00 = (vx0 & vy0) ? aw * (1.f - lx) * (1.f - ly) : 0.f;
        float w01 = (vx1 & vy0) ? aw * lx * (1.f - ly) : 0.f;
        float w10 = (vx0 & vy1) ? aw * (1.f - lx) * ly : 0.f;
        float w11 = (vx1 & vy1) ? aw * lx * ly : 0.f;
        int rowb = rb0 + offs2[lp];
        int col  = m * 32;
        int i00 = (rowb + y0c * W2 + x0c) * 256 + col;
        int i01 = (rowb + y0c * W2 + x1c) * 256 + col;
        int i10 = (rowb + y1c * W2 + x0c) * 256 + col;
        int i11 = (rowb + y1c * W2 + x1c) * 256 + col;
        sw[g][p][0] = w00; sw[g][p][1] = w01; sw[g][p][2] = w10; sw[g][p][3] = w11;
        sw[g][p][4] = __int_as_float(i00); sw[g][p][5] = __int_as_float(i01);
        sw[g][p][6] = __int_as_float(i10); sw[g][p][7] = __int_as_float(i11);
    }
    __syncthreads();

    int g = t >> 5, d = t & 31;
    float acc = 0.f;
    #pragma unroll
    for (int p = 0; p < 16; ++p) {
        float4 w  = *(const float4*)&sw[g][p][0];
        float4 fi = *(const float4*)&sw[g][p][4];
        int i00 = __float_as_int(fi.x), i01 = __float_as_int(fi.y);
        int i10 = __float_as_int(fi.z), i11 = __float_as_int(fi.w);
        acc = fmaf(w.x, bf2f(VPb[i00 + d]), acc);
        acc = fmaf(w.y, bf2f(VPb[i01 + d]), acc);
        acc = fmaf(w.z, bf2f(VPb[i10 + d]), acc);
        acc = fmaf(w.w, bf2f(VPb[i11 + d]), acc);
    }
    int grp = blk * 8 + g;
    int m2 = grp & 7, r2 = grp >> 3;
    unsigned short h = f2bf(acc);
    unsigned short lo = f2bf(acc - bf2f(h));
    // baked swizzle for GEMM2 A staging
    size_t base = (size_t)r2 * 256 + m2 * 32 + (((d >> 3) ^ ((r2 >> 1) & 3)) << 3) + (d & 7);
    att_hi[base] = h;
    att_lo[base] = lo;
}

// ---------------------------------------------------------------- GEMM2 (MFMA)
// out = att @ Wo^T + bo. A and B both prepacked; all global_load_lds. 3-product.
__global__ __launch_bounds__(256) void gemm2_mfma(
    const unsigned short* __restrict__ Ahi_g, const unsigned short* __restrict__ Alo_g,
    const unsigned short* __restrict__ Wohi, const unsigned short* __restrict__ Wolo,
    const float* __restrict__ bo, float* __restrict__ out) {
    __shared__ __align__(16) unsigned short Ah[4096], Al[4096], Bh[4096], Bl[4096];
    int t = threadIdx.x;
    int nb = blockIdx.x;                 // 0..1
    int r0 = blockIdx.y * 128;
    int w = t >> 6, lane = t & 63;
    int wr = w >> 1, wc = w & 1;
    int row_l = lane & 15, oct = lane >> 4;

    const unsigned short* Bbh = Wohi + (size_t)nb * 32768;
    const unsigned short* Bbl = Wolo + (size_t)nb * 32768;

    f4 acc[4][4];
    #pragma unroll
    for (int i = 0; i < 4; ++i)
        #pragma unroll
        for (int j = 0; j < 4; ++j) acc[i][j] = (f4){0.f, 0.f, 0.f, 0.f};

    int c0 = w * 64 + lane, c1 = c0 + 256;
    int ra0 = r0 + (c0 >> 2); if (ra0 >= BTOT) ra0 = BTOT - 1;
    int ra1 = r0 + (c1 >> 2); if (ra1 >= BTOT) ra1 = BTOT - 1;
    for (int kb = 0; kb < 8; ++kb) {
        __syncthreads();
        {
            size_t s0 = (size_t)ra0 * 256 + kb * 32 + (c0 & 3) * 8;
            size_t s1 = (size_t)ra1 * 256 + kb * 32 + (c1 & 3) * 8;
            __builtin_amdgcn_global_load_lds(Ahi_g + s0, &Ah[w * 512], 16, 0, 0);
            __builtin_amdgcn_global_load_lds(Ahi_g + s1, &Ah[2048 + w * 512], 16, 0, 0);
            __builtin_amdgcn_global_load_lds(Alo_g + s0, &Al[w * 512], 16, 0, 0);
            __builtin_amdgcn_global_load_lds(Alo_g + s1, &Al[2048 + w * 512], 16, 0, 0);
            __builtin_amdgcn_global_load_lds(Bbh + kb * 4096 + c0 * 8, &Bh[w * 512], 16, 0, 0);
            __builtin_amdgcn_global_load_lds(Bbh + kb * 4096 + c1 * 8, &Bh[2048 + w * 512], 16, 0, 0);
            __builtin_amdgcn_global_load_lds(Bbl + kb * 4096 + c0 * 8, &Bl[w * 512], 16, 0, 0);
            __builtin_amdgcn_global_load_lds(Bbl + kb * 4096 + c1 * 8, &Bl[2048 + w * 512], 16, 0, 0);
        }
        __syncthreads();
        bf8 ah[4], al[4], bh[4], bl[4];
        #pragma unroll
        for (int x = 0; x < 4; ++x) {
            int ri = wr * 64 + x * 16 + row_l;
            int ci = wc * 64 + x * 16 + row_l;
            ah[x] = *(const bf8*)(&Ah[ri * 32 + swzf(ri, oct) * 8]);
            al[x] = *(const bf8*)(&Al[ri * 32 + swzf(ri, oct) * 8]);
            bh[x] = *(const bf8*)(&Bh[ci * 32 + swzf(ci, oct) * 8]);
            bl[x] = *(const bf8*)(&Bl[ci * 32 + swzf(ci, oct) * 8]);
        }
        #pragma unroll
        for (int mi = 0; mi < 4; ++mi)
            #pragma unroll
            for (int ni = 0; ni < 4; ++ni) {
                f4 c = acc[mi][ni];
                c = __builtin_amdgcn_mfma_f32_16x16x32_bf16(ah[mi], bh[ni], c, 0, 0, 0);
                c = __builtin_amdgcn_mfma_f32_16x16x32_bf16(ah[mi], bl[ni], c, 0, 0, 0);
                c = __builtin_amdgcn_mfma_f32_16x16x32_bf16(al[mi], bh[ni], c, 0, 0, 0);
                acc[mi][ni] = c;
            }
    }
    #pragma unroll
    for (int ni = 0; ni < 4; ++ni) {
        int col = wc * 64 + ni * 16 + row_l;
        float bias = bo[nb * 128 + col];
        #pragma unroll
        for (int mi = 0; mi < 4; ++mi) {
            #pragma unroll
            for (int v = 0; v < 4; ++v) {
                int rr = r0 + wr * 64 + mi * 16 + oct * 4 + v;
                if (rr < BTOT)
                    out[(size_t)rr * 256 + nb * 128 + col] = acc[mi][ni][v] + bias;
            }
        }
    }
}

// ---------------------------------------------------------------- launch
extern "C" void kernel_launch(void* const* d_in, const int* in_sizes, int n_in,
                              void* d_out, int out_size, void* d_ws, size_t ws_size,
                              hipStream_t stream) {
    const float* v0 = (const float*)d_in[0];
    const float* p0 = (const float*)d_in[1];
    const float* v1 = (const float*)d_in[2];
    const float* p1 = (const float*)d_in[3];
    const float* v2 = (const float*)d_in[4];
    const float* p2 = (const float*)d_in[5];
    const float* v3 = (const float*)d_in[6];
    const float* p3 = (const float*)d_in[7];
    const float* Wv    = (const float*)d_in[8];
    const float* bv    = (const float*)d_in[9];
    const float* Wo    = (const float*)d_in[10];
    const float* bo    = (const float*)d_in[11];
    const float* Wbox  = (const float*)d_in[12];
    const float* bbox  = (const float*)d_in[13];
    const float* Wattn = (const float*)d_in[14];
    const float* battn = (const float*)d_in[15];
    float* out = (float*)d_out;

    char* ws = (char*)d_ws;
    unsigned short* W1hi = (unsigned short*)(ws);                  // 256KB
    unsigned short* W1lo = (unsigned short*)(ws + 262144);         // 256KB
    unsigned short* Wohi = (unsigned short*)(ws + 524288);         // 128KB
    unsigned short* Wolo = (unsigned short*)(ws + 655360);         // 128KB
    // A panels (27.26MB each); atth/attl alias them (dead after gemm1)
    unsigned short* Gv   = (unsigned short*)(ws + 1048576);
    unsigned short* Gq   = (unsigned short*)(ws + 1048576 + 27262976);
    unsigned short* atth = Gv;
    unsigned short* attl = Gq;
    unsigned short* VPb  = (unsigned short*)(ws + 1048576 + 2 * 27262976);          // 27.23MB
    float*          LB   = (float*)(ws + 1048576 + 2 * 27262976 + 27226112);        // 54.45MB

    convert_A<<<dim3(RPAD / 64), dim3(256), 0, stream>>>(v0, v1, v2, v3,
                                                         p0, p1, p2, p3, Gv, Gq);
    pack_weights<<<dim3(96), dim3(256), 0, stream>>>(Wv, Wattn, Wbox, Wo,
                                                     W1hi, W1lo, Wohi, Wolo);

    gemm1_mfma<<<dim3(4, RPAD / 128), dim3(256), 0, stream>>>(
        Gv, Gq, W1hi, W1lo, bv, battn, bbox, VPb, LB);

    sampler_kernel<<<dim3((BTOT * NH) / 8), dim3(256), 0, stream>>>(VPb, LB, atth, attl);

    gemm2_mfma<<<dim3(2, (BTOT + 127) / 128), dim3(256), 0, stream>>>(
        atth, attl, Wohi, Wolo, bo, out);
}

// Round 6
// 251.313 us; speedup vs baseline: 4.1246x; 1.2039x over previous
//
#include <hip/hip_runtime.h>
#include <cstdint>
#include <cmath>

#define D_MODEL 256
#define NH 8
#define NLVL 4
#define LTOT 13294
#define BATCH 4
#define BTOT (BATCH * LTOT)   // 53176
#define RPAD 53248             // 416 * 128 padded rows

typedef __attribute__((ext_vector_type(8))) short bf8;
typedef __attribute__((ext_vector_type(4))) float f4;

__device__ __forceinline__ unsigned short f2bf(float x) {
    unsigned u = __float_as_uint(x);
    u += 0x7fffu + ((u >> 16) & 1u);      // round-to-nearest-even
    return (unsigned short)(u >> 16);
}
__device__ __forceinline__ float bf2f(unsigned short h) {
    return __uint_as_float(((unsigned)h) << 16);
}
// chunk-slot swizzle: slot s of row i holds k-octet s ^ ((i>>1)&3)
__device__ __forceinline__ int swzf(int i, int s) { return s ^ ((i >> 1) & 3); }

// levels: (100,100),(50,50),(25,25),(13,13); offsets 0,10000,12500,13125
__device__ __forceinline__ void level_of(int l, int& lv, int& hw, int& Wl, int& HWl, int& loff) {
    if (l < 10000)      { lv = 0; loff = 0;     Wl = 100; HWl = 10000; }
    else if (l < 12500) { lv = 1; loff = 10000; Wl = 50;  HWl = 2500;  }
    else if (l < 13125) { lv = 2; loff = 12500; Wl = 25;  HWl = 625;   }
    else                { lv = 3; loff = 13125; Wl = 13;  HWl = 169;   }
    hw = l - loff;
}

// ---------------------------------------------------------------- pack weights
__global__ __launch_bounds__(256) void pack_weights(
    const float* __restrict__ Wv, const float* __restrict__ Wattn,
    const float* __restrict__ Wbox, const float* __restrict__ Wo,
    unsigned short* __restrict__ W1hi, unsigned short* __restrict__ W1lo,
    unsigned short* __restrict__ Wohi, unsigned short* __restrict__ Wolo) {
    int tid = blockIdx.x * 256 + threadIdx.x;
    const float* src;
    unsigned short *dh, *dl;
    int nb, kb, j, s;
    if (tid < 16384) {                       // GEMM1 B: 4 nb x 8 kb x 128 j x 4 s
        nb = tid >> 12; kb = (tid >> 9) & 7; j = (tid >> 2) & 127; s = tid & 3;
        int f = nb * 128 + j, c0 = kb * 32 + s * 8;
        if (f < 256)      src = Wv + (size_t)f * 256 + c0;
        else if (f < 384) src = Wattn + (size_t)(f - 256) * 256 + c0;
        else              src = Wbox + (size_t)(f - 384) * 256 + c0;
        dh = W1hi; dl = W1lo;
    } else if (tid < 24576) {                // GEMM2 B: 2 nb x 8 kb x 128 j x 4 s
        int t2 = tid - 16384;
        nb = t2 >> 12; kb = (t2 >> 9) & 7; j = (t2 >> 2) & 127; s = t2 & 3;
        int f = nb * 128 + j, c0 = kb * 32 + s * 8;
        src = Wo + (size_t)f * 256 + c0;
        dh = Wohi; dl = Wolo;
    } else return;
    int base = (((nb * 8 + kb) * 128 + j) * 4 + swzf(j, s)) * 8;
    #pragma unroll
    for (int e = 0; e < 8; ++e) {
        float x = src[e];
        unsigned short h = f2bf(x);
        dh[base + e] = h;
        dl[base + e] = f2bf(x - bf2f(h));
    }
}

// ---------------------------------------------------------------- convert A
__global__ __launch_bounds__(256) void convert_A(
    const float* __restrict__ v0, const float* __restrict__ v1,
    const float* __restrict__ v2, const float* __restrict__ v3,
    const float* __restrict__ p0, const float* __restrict__ p1,
    const float* __restrict__ p2, const float* __restrict__ p3,
    unsigned short* __restrict__ Gv, unsigned short* __restrict__ Gq) {
    __shared__ unsigned short HV[64][130];
    __shared__ unsigned short HQ[64][130];
    int t = threadIdx.x;
    int w = t >> 6, lane = t & 63;
    int r0 = blockIdx.x * 64;

    int r = r0 + lane; if (r >= BTOT) r = BTOT - 1;
    int b = r / LTOT, l = r % LTOT;
    int lv, hw, Wl, HWl, loff;
    level_of(l, lv, hw, Wl, HWl, loff);
    const float *vb, *pb;
    switch (lv) { case 0: vb = v0; pb = p0; break; case 1: vb = v1; pb = p1; break;
                  case 2: vb = v2; pb = p2; break; default: vb = v3; pb = p3; break; }
    size_t base = (size_t)b * D_MODEL * (size_t)HWl + (size_t)hw;
    vb += base; pb += base;

    int kb2 = (lane >> 2) & 3, slot = lane & 3;
    for (int h = 0; h < 2; ++h) {
        #pragma unroll 4
        for (int i = 0; i < 32; ++i) {
            int cl = i * 4 + w;
            int c = h * 128 + cl;
            float av = vb[(size_t)c * HWl];
            float aq = av + pb[(size_t)c * HWl];
            HV[lane][cl] = f2bf(av);
            HQ[lane][cl] = f2bf(aq);
        }
        __syncthreads();
        #pragma unroll
        for (int j = 0; j < 8; ++j) {
            int plane = j >> 2;
            int rl = (j & 3) * 16 + w * 4 + (lane >> 4);
            int oct = slot ^ ((rl >> 1) & 3);
            const unsigned* s32 = (const unsigned*)(plane ? &HQ[rl][kb2 * 32 + oct * 8]
                                                          : &HV[rl][kb2 * 32 + oct * 8]);
            uint4 vst = make_uint4(s32[0], s32[1], s32[2], s32[3]);
            unsigned short* dst = (plane ? Gq : Gv)
                + (size_t)(r0 + rl) * 256 + (h * 4 + kb2) * 32 + slot * 8;
            *(uint4*)dst = vst;
        }
        __syncthreads();
    }
}

// ---------------------------------------------------------------- GEMM1 (MFMA)
__global__ __launch_bounds__(256) void gemm1_mfma(
    const unsigned short* __restrict__ Gv, const unsigned short* __restrict__ Gq,
    const unsigned short* __restrict__ W1hi, const unsigned short* __restrict__ W1lo,
    const float* __restrict__ bv, const float* __restrict__ battn, const float* __restrict__ bbox,
    unsigned short* __restrict__ VPb, float* __restrict__ LB) {
    __shared__ __align__(16) unsigned short Ah[4096], Bh[4096], Bl[4096];
    int t = threadIdx.x;
    int nb = blockIdx.x;                 // 0..3
    int r0 = blockIdx.y * 128;
    const unsigned short* Asrc = (nb < 2) ? Gv : Gq;
    int w = t >> 6, lane = t & 63;
    int wr = w >> 1, wc = w & 1;
    int row_l = lane & 15, oct = lane >> 4;

    const unsigned short* Bbh = W1hi + (size_t)nb * 32768;
    const unsigned short* Bbl = W1lo + (size_t)nb * 32768;

    f4 acc[4][4];
    #pragma unroll
    for (int i = 0; i < 4; ++i)
        #pragma unroll
        for (int j = 0; j < 4; ++j) acc[i][j] = (f4){0.f, 0.f, 0.f, 0.f};

    int c0 = w * 64 + lane, c1 = c0 + 256;
    for (int kb = 0; kb < 8; ++kb) {
        __syncthreads();
        {
            const unsigned short* a0 = Asrc + (size_t)(r0 + (c0 >> 2)) * 256 + kb * 32 + (c0 & 3) * 8;
            const unsigned short* a1 = Asrc + (size_t)(r0 + (c1 >> 2)) * 256 + kb * 32 + (c1 & 3) * 8;
            __builtin_amdgcn_global_load_lds(a0, &Ah[w * 512], 16, 0, 0);
            __builtin_amdgcn_global_load_lds(a1, &Ah[2048 + w * 512], 16, 0, 0);
            const unsigned short* b0 = Bbh + kb * 4096 + c0 * 8;
            const unsigned short* b1 = Bbh + kb * 4096 + c1 * 8;
            __builtin_amdgcn_global_load_lds(b0, &Bh[w * 512], 16, 0, 0);
            __builtin_amdgcn_global_load_lds(b1, &Bh[2048 + w * 512], 16, 0, 0);
            const unsigned short* b2 = Bbl + kb * 4096 + c0 * 8;
            const unsigned short* b3 = Bbl + kb * 4096 + c1 * 8;
            __builtin_amdgcn_global_load_lds(b2, &Bl[w * 512], 16, 0, 0);
            __builtin_amdgcn_global_load_lds(b3, &Bl[2048 + w * 512], 16, 0, 0);
        }
        __syncthreads();
        bf8 a[4], bh[4], bl[4];
        #pragma unroll
        for (int x = 0; x < 4; ++x) {
            int ri = wr * 64 + x * 16 + row_l;
            int ci = wc * 64 + x * 16 + row_l;
            a[x]  = *(const bf8*)(&Ah[ri * 32 + swzf(ri, oct) * 8]);
            bh[x] = *(const bf8*)(&Bh[ci * 32 + swzf(ci, oct) * 8]);
            bl[x] = *(const bf8*)(&Bl[ci * 32 + swzf(ci, oct) * 8]);
        }
        #pragma unroll
        for (int mi = 0; mi < 4; ++mi)
            #pragma unroll
            for (int ni = 0; ni < 4; ++ni) {
                f4 c = acc[mi][ni];
                c = __builtin_amdgcn_mfma_f32_16x16x32_bf16(a[mi], bh[ni], c, 0, 0, 0);
                c = __builtin_amdgcn_mfma_f32_16x16x32_bf16(a[mi], bl[ni], c, 0, 0, 0);
                acc[mi][ni] = c;
            }
    }
    #pragma unroll
    for (int ni = 0; ni < 4; ++ni) {
        int col = wc * 64 + ni * 16 + row_l;
        float bias;
        if (nb == 0) bias = bv[col];
        else if (nb == 1) bias = bv[128 + col];
        else if (nb == 2) bias = battn[col];
        else bias = bbox[col];
        #pragma unroll
        for (int mi = 0; mi < 4; ++mi) {
            #pragma unroll
            for (int v = 0; v < 4; ++v) {
                int rr = r0 + wr * 64 + mi * 16 + oct * 4 + v;
                if (rr < BTOT) {
                    float val = acc[mi][ni][v] + bias;
                    if (nb < 2) VPb[(size_t)rr * 256 + nb * 128 + col] = f2bf(val);
                    else        LB[(size_t)rr * 256 + (nb - 2) * 128 + col] = val;
                }
            }
        }
    }
}

// ---------------------------------------------------------------- sampler v4
// Block = 256 threads = 16 groups. Phase 1: 16 grp x 16 pt (all threads) ->
// premultiplied weights + 4 BYTE offsets in LDS (544B group stride: conflict-
// free broadcast reads). Phase 2: 16 grp x 16 lanes, 2 channels/lane via dword
// gathers (u32 = 2 bf16), saddr-form loads.
__global__ __launch_bounds__(256) void sampler_kernel(const unsigned short* __restrict__ VPb,
                                                      const float* __restrict__ LB,
                                                      unsigned short* __restrict__ att_hi,
                                                      unsigned short* __restrict__ att_lo) {
    __shared__ float sw[16][17][8];  // [g][p][w00,w01,w10,w11, b00,b01,b10,b11]
    const int Ws2[4]   = {100, 50, 25, 13};
    const int offs2[4] = {0, 10000, 12500, 13125};
    int t = threadIdx.x;
    int blk = blockIdx.x;            // BTOT*NH/16 = 26588 blocks

    {
        int g = t >> 4, p = t & 15;
        int grp = blk * 16 + g;
        int m = grp & 7;
        int r = grp >> 3;
        int l = r % LTOT;
        int rb0 = r - l;

        int lv, hw, Wl, HWl, loff;
        level_of(l, lv, hw, Wl, HWl, loff);
        int x, y;
        switch (lv) {
            case 0:  y = hw / 100; x = hw - y * 100; break;
            case 1:  y = hw / 50;  x = hw - y * 50;  break;
            case 2:  y = hw / 25;  x = hw - y * 25;  break;
            default: y = hw / 13;  x = hw - y * 13;  break;
        }
        float denom = (float)((double)Wl + 1e-6);
        float cx = ((float)x + 0.5f) / denom;
        float cy = ((float)y + 0.5f) / denom;
        float rsw = 4.0f / (float)Wl;

        const float* Lrow = LB + (size_t)r * 256;
        float lg = Lrow[m * 16 + p];
        float mx = lg;
        #pragma unroll
        for (int off = 8; off >= 1; off >>= 1)
            mx = fmaxf(mx, __shfl_xor(mx, off, 16));
        float e = __expf(lg - mx);
        float ssum = e;
        #pragma unroll
        for (int off = 8; off >= 1; off >>= 1)
            ssum += __shfl_xor(ssum, off, 16);
        float aw = e / ssum;

        int lp = p >> 2, pp = p & 3;
        int W2 = Ws2[lp];
        float fW2 = (float)W2;
        float o0 = Lrow[128 + m * 16 + lp * 4 + 0];
        float o1 = Lrow[128 + m * 16 + lp * 4 + 1];
        float o2 = Lrow[128 + m * 16 + lp * 4 + 2];
        float o3 = Lrow[128 + m * 16 + lp * 4 + 3];
        float bcx = cx + o0 * 0.125f * rsw;
        float bcy = cy + o1 * 0.125f * rsw;
        float bsx = fmaxf(fmaf(o2 * 0.125f, rsw, rsw), 0.f);
        float bsy = fmaxf(fmaf(o3 * 0.125f, rsw, rsw), 0.f);
        float kx = (pp & 1)  ? 0.25f : -0.25f;
        float ky = (pp >> 1) ? 0.25f : -0.25f;
        float xs = fmaf(bcx + kx * bsx, fW2, -0.5f);
        float ys = fmaf(bcy + ky * bsy, fW2, -0.5f);
        float x0f = floorf(xs), y0f = floorf(ys);
        float lx = xs - x0f, ly = ys - y0f;
        int x0 = (int)x0f, y0 = (int)y0f;
        int x1 = x0 + 1, y1 = y0 + 1;
        bool vx0 = (x0 >= 0) & (x0 < W2), vx1 = (x1 >= 0) & (x1 < W2);
        bool vy0 = (y0 >= 0) & (y0 < W2), vy1 = (y1 >= 0) & (y1 < W2);
        int x0c = min(max(x0, 0), W2 - 1), x1c = min(max(x1, 0), W2 - 1);
        int y0c = min(max(y0, 0), W2 - 1), y1c = min(max(y1, 0), W2 - 1);
        float w00 = (vx0 & vy0) ? aw * (1.f - lx) * (1.f - ly) : 0.f;
        float w01 = (vx1 & vy0) ? aw * lx * (1.f - ly) : 0.f;
        float w10 = (vx0 & vy1) ? aw * (1.f - lx) * ly : 0.f;
        float w11 = (vx1 & vy1) ? aw * lx * ly : 0.f;
        int rowb = rb0 + offs2[lp];
        int col  = m * 32;
        int i00 = ((rowb + y0c * W2 + x0c) * 256 + col) * 2;   // BYTE offsets
        int i01 = ((rowb + y0c * W2 + x1c) * 256 + col) * 2;
        int i10 = ((rowb + y1c * W2 + x0c) * 256 + col) * 2;
        int i11 = ((rowb + y1c * W2 + x1c) * 256 + col) * 2;
        sw[g][p][0] = w00; sw[g][p][1] = w01; sw[g][p][2] = w10; sw[g][p][3] = w11;
        sw[g][p][4] = __int_as_float(i00); sw[g][p][5] = __int_as_float(i01);
        sw[g][p][6] = __int_as_float(i10); sw[g][p][7] = __int_as_float(i11);
    }
    __syncthreads();

    int g = t >> 4, lane16 = t & 15;
    unsigned dby = (unsigned)lane16 * 4u;          // 2 channels x 2B
    const char* Vb = (const char*)VPb;
    float acc0 = 0.f, acc1 = 0.f;
    #pragma unroll
    for (int p = 0; p < 16; ++p) {
        float4 w  = *(const float4*)&sw[g][p][0];
        float4 fi = *(const float4*)&sw[g][p][4];
        unsigned u0 = *(const unsigned*)(Vb + (size_t)(__float_as_uint(fi.x) + dby));
        unsigned u1 = *(const unsigned*)(Vb + (size_t)(__float_as_uint(fi.y) + dby));
        unsigned u2 = *(const unsigned*)(Vb + (size_t)(__float_as_uint(fi.z) + dby));
        unsigned u3 = *(const unsigned*)(Vb + (size_t)(__float_as_uint(fi.w) + dby));
        acc0 = fmaf(w.x, __uint_as_float(u0 << 16), acc0);
        acc1 = fmaf(w.x, __uint_as_float(u0 & 0xffff0000u), acc1);
        acc0 = fmaf(w.y, __uint_as_float(u1 << 16), acc0);
        acc1 = fmaf(w.y, __uint_as_float(u1 & 0xffff0000u), acc1);
        acc0 = fmaf(w.z, __uint_as_float(u2 << 16), acc0);
        acc1 = fmaf(w.z, __uint_as_float(u2 & 0xffff0000u), acc1);
        acc0 = fmaf(w.w, __uint_as_float(u3 << 16), acc0);
        acc1 = fmaf(w.w, __uint_as_float(u3 & 0xffff0000u), acc1);
    }
    int grp = blk * 16 + g;
    int m2 = grp & 7, r2 = grp >> 3;
    int d0 = lane16 * 2;
    unsigned short h0 = f2bf(acc0), h1 = f2bf(acc1);
    unsigned short l0 = f2bf(acc0 - bf2f(h0)), l1 = f2bf(acc1 - bf2f(h1));
    // baked swizzle for GEMM2 A staging (d0 even -> both channels in same octet)
    size_t base = (size_t)r2 * 256 + m2 * 32 + (((d0 >> 3) ^ ((r2 >> 1) & 3)) << 3) + (d0 & 7);
    *(unsigned*)&att_hi[base] = ((unsigned)h1 << 16) | (unsigned)h0;
    *(unsigned*)&att_lo[base] = ((unsigned)l1 << 16) | (unsigned)l0;
}

// ---------------------------------------------------------------- GEMM2 (MFMA)
__global__ __launch_bounds__(256) void gemm2_mfma(
    const unsigned short* __restrict__ Ahi_g, const unsigned short* __restrict__ Alo_g,
    const unsigned short* __restrict__ Wohi, const unsigned short* __restrict__ Wolo,
    const float* __restrict__ bo, float* __restrict__ out) {
    __shared__ __align__(16) unsigned short Ah[4096], Al[4096], Bh[4096], Bl[4096];
    int t = threadIdx.x;
    int nb = blockIdx.x;                 // 0..1
    int r0 = blockIdx.y * 128;
    int w = t >> 6, lane = t & 63;
    int wr = w >> 1, wc = w & 1;
    int row_l = lane & 15, oct = lane >> 4;

    const unsigned short* Bbh = Wohi + (size_t)nb * 32768;
    const unsigned short* Bbl = Wolo + (size_t)nb * 32768;

    f4 acc[4][4];
    #pragma unroll
    for (int i = 0; i < 4; ++i)
        #pragma unroll
        for (int j = 0; j < 4; ++j) acc[i][j] = (f4){0.f, 0.f, 0.f, 0.f};

    int c0 = w * 64 + lane, c1 = c0 + 256;
    int ra0 = r0 + (c0 >> 2); if (ra0 >= BTOT) ra0 = BTOT - 1;
    int ra1 = r0 + (c1 >> 2); if (ra1 >= BTOT) ra1 = BTOT - 1;
    for (int kb = 0; kb < 8; ++kb) {
        __syncthreads();
        {
            size_t s0 = (size_t)ra0 * 256 + kb * 32 + (c0 & 3) * 8;
            size_t s1 = (size_t)ra1 * 256 + kb * 32 + (c1 & 3) * 8;
            __builtin_amdgcn_global_load_lds(Ahi_g + s0, &Ah[w * 512], 16, 0, 0);
            __builtin_amdgcn_global_load_lds(Ahi_g + s1, &Ah[2048 + w * 512], 16, 0, 0);
            __builtin_amdgcn_global_load_lds(Alo_g + s0, &Al[w * 512], 16, 0, 0);
            __builtin_amdgcn_global_load_lds(Alo_g + s1, &Al[2048 + w * 512], 16, 0, 0);
            __builtin_amdgcn_global_load_lds(Bbh + kb * 4096 + c0 * 8, &Bh[w * 512], 16, 0, 0);
            __builtin_amdgcn_global_load_lds(Bbh + kb * 4096 + c1 * 8, &Bh[2048 + w * 512], 16, 0, 0);
            __builtin_amdgcn_global_load_lds(Bbl + kb * 4096 + c0 * 8, &Bl[w * 512], 16, 0, 0);
            __builtin_amdgcn_global_load_lds(Bbl + kb * 4096 + c1 * 8, &Bl[2048 + w * 512], 16, 0, 0);
        }
        __syncthreads();
        bf8 ah[4], al[4], bh[4], bl[4];
        #pragma unroll
        for (int x = 0; x < 4; ++x) {
            int ri = wr * 64 + x * 16 + row_l;
            int ci = wc * 64 + x * 16 + row_l;
            ah[x] = *(const bf8*)(&Ah[ri * 32 + swzf(ri, oct) * 8]);
            al[x] = *(const bf8*)(&Al[ri * 32 + swzf(ri, oct) * 8]);
            bh[x] = *(const bf8*)(&Bh[ci * 32 + swzf(ci, oct) * 8]);
            bl[x] = *(const bf8*)(&Bl[ci * 32 + swzf(ci, oct) * 8]);
        }
        #pragma unroll
        for (int mi = 0; mi < 4; ++mi)
            #pragma unroll
            for (int ni = 0; ni < 4; ++ni) {
                f4 c = acc[mi][ni];
                c = __builtin_amdgcn_mfma_f32_16x16x32_bf16(ah[mi], bh[ni], c, 0, 0, 0);
                c = __builtin_amdgcn_mfma_f32_16x16x32_bf16(ah[mi], bl[ni], c, 0, 0, 0);
                c = __builtin_amdgcn_mfma_f32_16x16x32_bf16(al[mi], bh[ni], c, 0, 0, 0);
                acc[mi][ni] = c;
            }
    }
    #pragma unroll
    for (int ni = 0; ni < 4; ++ni) {
        int col = wc * 64 + ni * 16 + row_l;
        float bias = bo[nb * 128 + col];
        #pragma unroll
        for (int mi = 0; mi < 4; ++mi) {
            #pragma unroll
            for (int v = 0; v < 4; ++v) {
                int rr = r0 + wr * 64 + mi * 16 + oct * 4 + v;
                if (rr < BTOT)
                    out[(size_t)rr * 256 + nb * 128 + col] = acc[mi][ni][v] + bias;
            }
        }
    }
}

// ---------------------------------------------------------------- launch
extern "C" void kernel_launch(void* const* d_in, const int* in_sizes, int n_in,
                              void* d_out, int out_size, void* d_ws, size_t ws_size,
                              hipStream_t stream) {
    const float* v0 = (const float*)d_in[0];
    const float* p0 = (const float*)d_in[1];
    const float* v1 = (const float*)d_in[2];
    const float* p1 = (const float*)d_in[3];
    const float* v2 = (const float*)d_in[4];
    const float* p2 = (const float*)d_in[5];
    const float* v3 = (const float*)d_in[6];
    const float* p3 = (const float*)d_in[7];
    const float* Wv    = (const float*)d_in[8];
    const float* bv    = (const float*)d_in[9];
    const float* Wo    = (const float*)d_in[10];
    const float* bo    = (const float*)d_in[11];
    const float* Wbox  = (const float*)d_in[12];
    const float* bbox  = (const float*)d_in[13];
    const float* Wattn = (const float*)d_in[14];
    const float* battn = (const float*)d_in[15];
    float* out = (float*)d_out;

    char* ws = (char*)d_ws;
    unsigned short* W1hi = (unsigned short*)(ws);                  // 256KB
    unsigned short* W1lo = (unsigned short*)(ws + 262144);         // 256KB
    unsigned short* Wohi = (unsigned short*)(ws + 524288);         // 128KB
    unsigned short* Wolo = (unsigned short*)(ws + 655360);         // 128KB
    // A panels (27.26MB each); atth/attl alias them (dead after gemm1)
    unsigned short* Gv   = (unsigned short*)(ws + 1048576);
    unsigned short* Gq   = (unsigned short*)(ws + 1048576 + 27262976);
    unsigned short* atth = Gv;
    unsigned short* attl = Gq;
    unsigned short* VPb  = (unsigned short*)(ws + 1048576 + 2 * 27262976);          // 27.23MB
    float*          LB   = (float*)(ws + 1048576 + 2 * 27262976 + 27226112);        // 54.45MB

    convert_A<<<dim3(RPAD / 64), dim3(256), 0, stream>>>(v0, v1, v2, v3,
                                                         p0, p1, p2, p3, Gv, Gq);
    pack_weights<<<dim3(96), dim3(256), 0, stream>>>(Wv, Wattn, Wbox, Wo,
                                                     W1hi, W1lo, Wohi, Wolo);

    gemm1_mfma<<<dim3(4, RPAD / 128), dim3(256), 0, stream>>>(
        Gv, Gq, W1hi, W1lo, bv, battn, bbox, VPb, LB);

    sampler_kernel<<<dim3((BTOT * NH) / 16), dim3(256), 0, stream>>>(VPb, LB, atth, attl);

    gemm2_mfma<<<dim3(2, (BTOT + 127) / 128), dim3(256), 0, stream>>>(
        atth, attl, Wohi, Wolo, bo, out);
}

// Round 7
// 245.485 us; speedup vs baseline: 4.2225x; 1.0237x over previous
//
#include <hip/hip_runtime.h>
#include <cstdint>
#include <cmath>

#define D_MODEL 256
#define NH 8
#define NLVL 4
#define LTOT 13294
#define BATCH 4
#define BTOT (BATCH * LTOT)   // 53176
#define RPAD 53248             // 416 * 128 padded rows

typedef __attribute__((ext_vector_type(8))) short bf8;
typedef __attribute__((ext_vector_type(4))) float f4;
typedef __attribute__((ext_vector_type(2))) float f2;

__device__ __forceinline__ unsigned short f2bf(float x) {
    unsigned u = __float_as_uint(x);
    u += 0x7fffu + ((u >> 16) & 1u);      // round-to-nearest-even
    return (unsigned short)(u >> 16);
}
__device__ __forceinline__ float bf2f(unsigned short h) {
    return __uint_as_float(((unsigned)h) << 16);
}
// chunk-slot swizzle: slot s of row i holds k-octet s ^ ((i>>1)&3)
__device__ __forceinline__ int swzf(int i, int s) { return s ^ ((i >> 1) & 3); }

// levels: (100,100),(50,50),(25,25),(13,13); offsets 0,10000,12500,13125
__device__ __forceinline__ void level_of(int l, int& lv, int& hw, int& Wl, int& HWl, int& loff) {
    if (l < 10000)      { lv = 0; loff = 0;     Wl = 100; HWl = 10000; }
    else if (l < 12500) { lv = 1; loff = 10000; Wl = 50;  HWl = 2500;  }
    else if (l < 13125) { lv = 2; loff = 12500; Wl = 25;  HWl = 625;   }
    else                { lv = 3; loff = 13125; Wl = 13;  HWl = 169;   }
    hw = l - loff;
}

// ---------------------------------------------------------------- pack weights
__global__ __launch_bounds__(256) void pack_weights(
    const float* __restrict__ Wv, const float* __restrict__ Wattn,
    const float* __restrict__ Wbox, const float* __restrict__ Wo,
    unsigned short* __restrict__ W1hi, unsigned short* __restrict__ W1lo,
    unsigned short* __restrict__ Wohi, unsigned short* __restrict__ Wolo) {
    int tid = blockIdx.x * 256 + threadIdx.x;
    const float* src;
    unsigned short *dh, *dl;
    int nb, kb, j, s;
    if (tid < 16384) {                       // GEMM1 B: 4 nb x 8 kb x 128 j x 4 s
        nb = tid >> 12; kb = (tid >> 9) & 7; j = (tid >> 2) & 127; s = tid & 3;
        int f = nb * 128 + j, c0 = kb * 32 + s * 8;
        if (f < 256)      src = Wv + (size_t)f * 256 + c0;
        else if (f < 384) src = Wattn + (size_t)(f - 256) * 256 + c0;
        else              src = Wbox + (size_t)(f - 384) * 256 + c0;
        dh = W1hi; dl = W1lo;
    } else if (tid < 24576) {                // GEMM2 B: 2 nb x 8 kb x 128 j x 4 s
        int t2 = tid - 16384;
        nb = t2 >> 12; kb = (t2 >> 9) & 7; j = (t2 >> 2) & 127; s = t2 & 3;
        int f = nb * 128 + j, c0 = kb * 32 + s * 8;
        src = Wo + (size_t)f * 256 + c0;
        dh = Wohi; dl = Wolo;
    } else return;
    int base = (((nb * 8 + kb) * 128 + j) * 4 + swzf(j, s)) * 8;
    #pragma unroll
    for (int e = 0; e < 8; ++e) {
        float x = src[e];
        unsigned short h = f2bf(x);
        dh[base + e] = h;
        dl[base + e] = f2bf(x - bf2f(h));
    }
}

// ---------------------------------------------------------------- convert A
__global__ __launch_bounds__(256) void convert_A(
    const float* __restrict__ v0, const float* __restrict__ v1,
    const float* __restrict__ v2, const float* __restrict__ v3,
    const float* __restrict__ p0, const float* __restrict__ p1,
    const float* __restrict__ p2, const float* __restrict__ p3,
    unsigned short* __restrict__ Gv, unsigned short* __restrict__ Gq) {
    __shared__ unsigned short HV[64][130];
    __shared__ unsigned short HQ[64][130];
    int t = threadIdx.x;
    int w = t >> 6, lane = t & 63;
    int r0 = blockIdx.x * 64;

    int r = r0 + lane; if (r >= BTOT) r = BTOT - 1;
    int b = r / LTOT, l = r % LTOT;
    int lv, hw, Wl, HWl, loff;
    level_of(l, lv, hw, Wl, HWl, loff);
    const float *vb, *pb;
    switch (lv) { case 0: vb = v0; pb = p0; break; case 1: vb = v1; pb = p1; break;
                  case 2: vb = v2; pb = p2; break; default: vb = v3; pb = p3; break; }
    size_t base = (size_t)b * D_MODEL * (size_t)HWl + (size_t)hw;
    vb += base; pb += base;

    int kb2 = (lane >> 2) & 3, slot = lane & 3;
    for (int h = 0; h < 2; ++h) {
        #pragma unroll 4
        for (int i = 0; i < 32; ++i) {
            int cl = i * 4 + w;
            int c = h * 128 + cl;
            float av = vb[(size_t)c * HWl];
            float aq = av + pb[(size_t)c * HWl];
            HV[lane][cl] = f2bf(av);
            HQ[lane][cl] = f2bf(aq);
        }
        __syncthreads();
        #pragma unroll
        for (int j = 0; j < 8; ++j) {
            int plane = j >> 2;
            int rl = (j & 3) * 16 + w * 4 + (lane >> 4);
            int oct = slot ^ ((rl >> 1) & 3);
            const unsigned* s32 = (const unsigned*)(plane ? &HQ[rl][kb2 * 32 + oct * 8]
                                                          : &HV[rl][kb2 * 32 + oct * 8]);
            uint4 vst = make_uint4(s32[0], s32[1], s32[2], s32[3]);
            unsigned short* dst = (plane ? Gq : Gv)
                + (size_t)(r0 + rl) * 256 + (h * 4 + kb2) * 32 + slot * 8;
            *(uint4*)dst = vst;
        }
        __syncthreads();
    }
}

// ---------------------------------------------------------------- GEMM1 (MFMA)
// Double-buffered: 1 barrier/K-step, prefetch tile k+1 during compute of k.
__global__ __launch_bounds__(256) void gemm1_mfma(
    const unsigned short* __restrict__ Gv, const unsigned short* __restrict__ Gq,
    const unsigned short* __restrict__ W1hi, const unsigned short* __restrict__ W1lo,
    const float* __restrict__ bv, const float* __restrict__ battn, const float* __restrict__ bbox,
    unsigned short* __restrict__ VPb, float* __restrict__ LB) {
    __shared__ __align__(16) unsigned short Ah[2][4096], Bh[2][4096], Bl[2][4096];
    int t = threadIdx.x;
    int nb = blockIdx.x;                 // 0..3
    int r0 = blockIdx.y * 128;
    const unsigned short* Asrc = (nb < 2) ? Gv : Gq;
    int w = t >> 6, lane = t & 63;
    int wr = w >> 1, wc = w & 1;
    int row_l = lane & 15, oct = lane >> 4;

    const unsigned short* Bbh = W1hi + (size_t)nb * 32768;
    const unsigned short* Bbl = W1lo + (size_t)nb * 32768;

    f4 acc[4][4];
    #pragma unroll
    for (int i = 0; i < 4; ++i)
        #pragma unroll
        for (int j = 0; j < 4; ++j) acc[i][j] = (f4){0.f, 0.f, 0.f, 0.f};

    int c0 = w * 64 + lane, c1 = c0 + 256;
    const unsigned short* a0b = Asrc + (size_t)(r0 + (c0 >> 2)) * 256 + (c0 & 3) * 8;
    const unsigned short* a1b = Asrc + (size_t)(r0 + (c1 >> 2)) * 256 + (c1 & 3) * 8;

#define G1_STAGE(bb, kb)                                                            \
    {                                                                               \
        __builtin_amdgcn_global_load_lds(a0b + (kb) * 32, &Ah[bb][w * 512], 16, 0, 0);        \
        __builtin_amdgcn_global_load_lds(a1b + (kb) * 32, &Ah[bb][2048 + w * 512], 16, 0, 0); \
        __builtin_amdgcn_global_load_lds(Bbh + (kb) * 4096 + c0 * 8, &Bh[bb][w * 512], 16, 0, 0);        \
        __builtin_amdgcn_global_load_lds(Bbh + (kb) * 4096 + c1 * 8, &Bh[bb][2048 + w * 512], 16, 0, 0); \
        __builtin_amdgcn_global_load_lds(Bbl + (kb) * 4096 + c0 * 8, &Bl[bb][w * 512], 16, 0, 0);        \
        __builtin_amdgcn_global_load_lds(Bbl + (kb) * 4096 + c1 * 8, &Bl[bb][2048 + w * 512], 16, 0, 0); \
    }

    G1_STAGE(0, 0);
    for (int kb = 0; kb < 8; ++kb) {
        __syncthreads();                       // drains prefetch; buf kb ready
        if (kb < 7) G1_STAGE((kb + 1) & 1, kb + 1);
        int bb = kb & 1;
        bf8 a[4], bh[4], bl[4];
        #pragma unroll
        for (int x = 0; x < 4; ++x) {
            int ri = wr * 64 + x * 16 + row_l;
            int ci = wc * 64 + x * 16 + row_l;
            a[x]  = *(const bf8*)(&Ah[bb][ri * 32 + swzf(ri, oct) * 8]);
            bh[x] = *(const bf8*)(&Bh[bb][ci * 32 + swzf(ci, oct) * 8]);
            bl[x] = *(const bf8*)(&Bl[bb][ci * 32 + swzf(ci, oct) * 8]);
        }
        #pragma unroll
        for (int mi = 0; mi < 4; ++mi)
            #pragma unroll
            for (int ni = 0; ni < 4; ++ni) {
                f4 c = acc[mi][ni];
                c = __builtin_amdgcn_mfma_f32_16x16x32_bf16(a[mi], bh[ni], c, 0, 0, 0);
                c = __builtin_amdgcn_mfma_f32_16x16x32_bf16(a[mi], bl[ni], c, 0, 0, 0);
                acc[mi][ni] = c;
            }
    }
    #pragma unroll
    for (int ni = 0; ni < 4; ++ni) {
        int col = wc * 64 + ni * 16 + row_l;
        float bias;
        if (nb == 0) bias = bv[col];
        else if (nb == 1) bias = bv[128 + col];
        else if (nb == 2) bias = battn[col];
        else bias = bbox[col];
        #pragma unroll
        for (int mi = 0; mi < 4; ++mi) {
            #pragma unroll
            for (int v = 0; v < 4; ++v) {
                int rr = r0 + wr * 64 + mi * 16 + oct * 4 + v;
                if (rr < BTOT) {
                    float val = acc[mi][ni][v] + bias;
                    if (nb < 2) VPb[(size_t)rr * 256 + nb * 128 + col] = f2bf(val);
                    else        LB[(size_t)rr * 256 + (nb - 2) * 128 + col] = val;
                }
            }
        }
    }
}

// ---------------------------------------------------------------- sampler v5
// Block = 256 threads = 16 groups. Phase 1: 16 grp x 16 pt -> LDS: duplicated
// weight pairs (float2-ready) + 4 byte offsets. Phase 2: 16 lanes/group,
// 2 channels/lane via dword gathers, packed f32 fma (v_pk_fma_f32).
__global__ __launch_bounds__(256) void sampler_kernel(const unsigned short* __restrict__ VPb,
                                                      const float* __restrict__ LB,
                                                      unsigned short* __restrict__ att_hi,
                                                      unsigned short* __restrict__ att_lo) {
    __shared__ float sw[16][260];    // per group: 16 pts x 16 floats (+4 pad)
    const int Ws2[4]   = {100, 50, 25, 13};
    const int offs2[4] = {0, 10000, 12500, 13125};
    int t = threadIdx.x;
    int blk = blockIdx.x;            // BTOT*NH/16 = 26588 blocks

    {
        int g = t >> 4, p = t & 15;
        int grp = blk * 16 + g;
        int m = grp & 7;
        int r = grp >> 3;
        int l = r % LTOT;
        int rb0 = r - l;

        int lv, hw, Wl, HWl, loff;
        level_of(l, lv, hw, Wl, HWl, loff);
        int x, y;
        switch (lv) {
            case 0:  y = hw / 100; x = hw - y * 100; break;
            case 1:  y = hw / 50;  x = hw - y * 50;  break;
            case 2:  y = hw / 25;  x = hw - y * 25;  break;
            default: y = hw / 13;  x = hw - y * 13;  break;
        }
        float denom = (float)((double)Wl + 1e-6);
        float cx = ((float)x + 0.5f) / denom;
        float cy = ((float)y + 0.5f) / denom;
        float rsw = 4.0f / (float)Wl;

        const float* Lrow = LB + (size_t)r * 256;
        float lg = Lrow[m * 16 + p];
        float mx = lg;
        #pragma unroll
        for (int off = 8; off >= 1; off >>= 1)
            mx = fmaxf(mx, __shfl_xor(mx, off, 16));
        float e = __expf(lg - mx);
        float ssum = e;
        #pragma unroll
        for (int off = 8; off >= 1; off >>= 1)
            ssum += __shfl_xor(ssum, off, 16);
        float aw = e / ssum;

        int lp = p >> 2, pp = p & 3;
        int W2 = Ws2[lp];
        float fW2 = (float)W2;
        float o0 = Lrow[128 + m * 16 + lp * 4 + 0];
        float o1 = Lrow[128 + m * 16 + lp * 4 + 1];
        float o2 = Lrow[128 + m * 16 + lp * 4 + 2];
        float o3 = Lrow[128 + m * 16 + lp * 4 + 3];
        float bcx = cx + o0 * 0.125f * rsw;
        float bcy = cy + o1 * 0.125f * rsw;
        float bsx = fmaxf(fmaf(o2 * 0.125f, rsw, rsw), 0.f);
        float bsy = fmaxf(fmaf(o3 * 0.125f, rsw, rsw), 0.f);
        float kx = (pp & 1)  ? 0.25f : -0.25f;
        float ky = (pp >> 1) ? 0.25f : -0.25f;
        float xs = fmaf(bcx + kx * bsx, fW2, -0.5f);
        float ys = fmaf(bcy + ky * bsy, fW2, -0.5f);
        float x0f = floorf(xs), y0f = floorf(ys);
        float lx = xs - x0f, ly = ys - y0f;
        int x0 = (int)x0f, y0 = (int)y0f;
        int x1 = x0 + 1, y1 = y0 + 1;
        bool vx0 = (x0 >= 0) & (x0 < W2), vx1 = (x1 >= 0) & (x1 < W2);
        bool vy0 = (y0 >= 0) & (y0 < W2), vy1 = (y1 >= 0) & (y1 < W2);
        int x0c = min(max(x0, 0), W2 - 1), x1c = min(max(x1, 0), W2 - 1);
        int y0c = min(max(y0, 0), W2 - 1), y1c = min(max(y1, 0), W2 - 1);
        float w00 = (vx0 & vy0) ? aw * (1.f - lx) * (1.f - ly) : 0.f;
        float w01 = (vx1 & vy0) ? aw * lx * (1.f - ly) : 0.f;
        float w10 = (vx0 & vy1) ? aw * (1.f - lx) * ly : 0.f;
        float w11 = (vx1 & vy1) ? aw * lx * ly : 0.f;
        int rowb = rb0 + offs2[lp];
        int col  = m * 32;
        int i00 = ((rowb + y0c * W2 + x0c) * 256 + col) * 2;   // BYTE offsets
        int i01 = ((rowb + y0c * W2 + x1c) * 256 + col) * 2;
        int i10 = ((rowb + y1c * W2 + x0c) * 256 + col) * 2;
        int i11 = ((rowb + y1c * W2 + x1c) * 256 + col) * 2;
        float* dst = &sw[g][p * 16];
        dst[0] = w00; dst[1] = w00; dst[2] = w01; dst[3] = w01;
        dst[4] = w10; dst[5] = w10; dst[6] = w11; dst[7] = w11;
        dst[8]  = __int_as_float(i00); dst[9]  = __int_as_float(i01);
        dst[10] = __int_as_float(i10); dst[11] = __int_as_float(i11);
    }
    __syncthreads();

    int g = t >> 4, lane16 = t & 15;
    unsigned dby = (unsigned)lane16 * 4u;          // 2 channels x 2B
    const char* Vb = (const char*)VPb;
    f2 acc2 = {0.f, 0.f};
    #pragma unroll
    for (int p = 0; p < 16; ++p) {
        const float* sp = &sw[g][p * 16];
        float4 wA = *(const float4*)sp;            // w00,w00,w01,w01
        float4 wB = *(const float4*)(sp + 4);      // w10,w10,w11,w11
        float4 fi = *(const float4*)(sp + 8);
        unsigned u0 = *(const unsigned*)(Vb + (size_t)(__float_as_uint(fi.x) + dby));
        unsigned u1 = *(const unsigned*)(Vb + (size_t)(__float_as_uint(fi.y) + dby));
        unsigned u2 = *(const unsigned*)(Vb + (size_t)(__float_as_uint(fi.z) + dby));
        unsigned u3 = *(const unsigned*)(Vb + (size_t)(__float_as_uint(fi.w) + dby));
        f2 v00 = {__uint_as_float(u0 << 16), __uint_as_float(u0 & 0xffff0000u)};
        f2 v01 = {__uint_as_float(u1 << 16), __uint_as_float(u1 & 0xffff0000u)};
        f2 v10 = {__uint_as_float(u2 << 16), __uint_as_float(u2 & 0xffff0000u)};
        f2 v11 = {__uint_as_float(u3 << 16), __uint_as_float(u3 & 0xffff0000u)};
        acc2 = __builtin_elementwise_fma((f2){wA.x, wA.y}, v00, acc2);
        acc2 = __builtin_elementwise_fma((f2){wA.z, wA.w}, v01, acc2);
        acc2 = __builtin_elementwise_fma((f2){wB.x, wB.y}, v10, acc2);
        acc2 = __builtin_elementwise_fma((f2){wB.z, wB.w}, v11, acc2);
    }
    int grp = blk * 16 + g;
    int m2 = grp & 7, r2 = grp >> 3;
    int d0 = lane16 * 2;
    unsigned short h0 = f2bf(acc2.x), h1 = f2bf(acc2.y);
    unsigned short l0 = f2bf(acc2.x - bf2f(h0)), l1 = f2bf(acc2.y - bf2f(h1));
    // baked swizzle for GEMM2 A staging (d0 even -> both channels in same octet)
    size_t base = (size_t)r2 * 256 + m2 * 32 + (((d0 >> 3) ^ ((r2 >> 1) & 3)) << 3) + (d0 & 7);
    *(unsigned*)&att_hi[base] = ((unsigned)h1 << 16) | (unsigned)h0;
    *(unsigned*)&att_lo[base] = ((unsigned)l1 << 16) | (unsigned)l0;
}

// ---------------------------------------------------------------- GEMM2 (MFMA)
// Double-buffered, 1 barrier/K-step.
__global__ __launch_bounds__(256) void gemm2_mfma(
    const unsigned short* __restrict__ Ahi_g, const unsigned short* __restrict__ Alo_g,
    const unsigned short* __restrict__ Wohi, const unsigned short* __restrict__ Wolo,
    const float* __restrict__ bo, float* __restrict__ out) {
    __shared__ __align__(16) unsigned short Ah[2][4096], Al[2][4096], Bh[2][4096], Bl[2][4096];
    int t = threadIdx.x;
    int nb = blockIdx.x;                 // 0..1
    int r0 = blockIdx.y * 128;
    int w = t >> 6, lane = t & 63;
    int wr = w >> 1, wc = w & 1;
    int row_l = lane & 15, oct = lane >> 4;

    const unsigned short* Bbh = Wohi + (size_t)nb * 32768;
    const unsigned short* Bbl = Wolo + (size_t)nb * 32768;

    f4 acc[4][4];
    #pragma unroll
    for (int i = 0; i < 4; ++i)
        #pragma unroll
        for (int j = 0; j < 4; ++j) acc[i][j] = (f4){0.f, 0.f, 0.f, 0.f};

    int c0 = w * 64 + lane, c1 = c0 + 256;
    int ra0 = r0 + (c0 >> 2); if (ra0 >= BTOT) ra0 = BTOT - 1;
    int ra1 = r0 + (c1 >> 2); if (ra1 >= BTOT) ra1 = BTOT - 1;
    const unsigned short* ah0 = Ahi_g + (size_t)ra0 * 256 + (c0 & 3) * 8;
    const unsigned short* ah1 = Ahi_g + (size_t)ra1 * 256 + (c1 & 3) * 8;
    const unsigned short* al0 = Alo_g + (size_t)ra0 * 256 + (c0 & 3) * 8;
    const unsigned short* al1 = Alo_g + (size_t)ra1 * 256 + (c1 & 3) * 8;

#define G2_STAGE(bb, kb)                                                            \
    {                                                                               \
        __builtin_amdgcn_global_load_lds(ah0 + (kb) * 32, &Ah[bb][w * 512], 16, 0, 0);        \
        __builtin_amdgcn_global_load_lds(ah1 + (kb) * 32, &Ah[bb][2048 + w * 512], 16, 0, 0); \
        __builtin_amdgcn_global_load_lds(al0 + (kb) * 32, &Al[bb][w * 512], 16, 0, 0);        \
        __builtin_amdgcn_global_load_lds(al1 + (kb) * 32, &Al[bb][2048 + w * 512], 16, 0, 0); \
        __builtin_amdgcn_global_load_lds(Bbh + (kb) * 4096 + c0 * 8, &Bh[bb][w * 512], 16, 0, 0);        \
        __builtin_amdgcn_global_load_lds(Bbh + (kb) * 4096 + c1 * 8, &Bh[bb][2048 + w * 512], 16, 0, 0); \
        __builtin_amdgcn_global_load_lds(Bbl + (kb) * 4096 + c0 * 8, &Bl[bb][w * 512], 16, 0, 0);        \
        __builtin_amdgcn_global_load_lds(Bbl + (kb) * 4096 + c1 * 8, &Bl[bb][2048 + w * 512], 16, 0, 0); \
    }

    G2_STAGE(0, 0);
    for (int kb = 0; kb < 8; ++kb) {
        __syncthreads();
        if (kb < 7) G2_STAGE((kb + 1) & 1, kb + 1);
        int bb = kb & 1;
        bf8 ah[4], al[4], bh[4], bl[4];
        #pragma unroll
        for (int x = 0; x < 4; ++x) {
            int ri = wr * 64 + x * 16 + row_l;
            int ci = wc * 64 + x * 16 + row_l;
            ah[x] = *(const bf8*)(&Ah[bb][ri * 32 + swzf(ri, oct) * 8]);
            al[x] = *(const bf8*)(&Al[bb][ri * 32 + swzf(ri, oct) * 8]);
            bh[x] = *(const bf8*)(&Bh[bb][ci * 32 + swzf(ci, oct) * 8]);
            bl[x] = *(const bf8*)(&Bl[bb][ci * 32 + swzf(ci, oct) * 8]);
        }
        #pragma unroll
        for (int mi = 0; mi < 4; ++mi)
            #pragma unroll
            for (int ni = 0; ni < 4; ++ni) {
                f4 c = acc[mi][ni];
                c = __builtin_amdgcn_mfma_f32_16x16x32_bf16(ah[mi], bh[ni], c, 0, 0, 0);
                c = __builtin_amdgcn_mfma_f32_16x16x32_bf16(ah[mi], bl[ni], c, 0, 0, 0);
                c = __builtin_amdgcn_mfma_f32_16x16x32_bf16(al[mi], bh[ni], c, 0, 0, 0);
                acc[mi][ni] = c;
            }
    }
    #pragma unroll
    for (int ni = 0; ni < 4; ++ni) {
        int col = wc * 64 + ni * 16 + row_l;
        float bias = bo[nb * 128 + col];
        #pragma unroll
        for (int mi = 0; mi < 4; ++mi) {
            #pragma unroll
            for (int v = 0; v < 4; ++v) {
                int rr = r0 + wr * 64 + mi * 16 + oct * 4 + v;
                if (rr < BTOT)
                    out[(size_t)rr * 256 + nb * 128 + col] = acc[mi][ni][v] + bias;
            }
        }
    }
}

// ---------------------------------------------------------------- launch
extern "C" void kernel_launch(void* const* d_in, const int* in_sizes, int n_in,
                              void* d_out, int out_size, void* d_ws, size_t ws_size,
                              hipStream_t stream) {
    const float* v0 = (const float*)d_in[0];
    const float* p0 = (const float*)d_in[1];
    const float* v1 = (const float*)d_in[2];
    const float* p1 = (const float*)d_in[3];
    const float* v2 = (const float*)d_in[4];
    const float* p2 = (const float*)d_in[5];
    const float* v3 = (const float*)d_in[6];
    const float* p3 = (const float*)d_in[7];
    const float* Wv    = (const float*)d_in[8];
    const float* bv    = (const float*)d_in[9];
    const float* Wo    = (const float*)d_in[10];
    const float* bo    = (const float*)d_in[11];
    const float* Wbox  = (const float*)d_in[12];
    const float* bbox  = (const float*)d_in[13];
    const float* Wattn = (const float*)d_in[14];
    const float* battn = (const float*)d_in[15];
    float* out = (float*)d_out;

    char* ws = (char*)d_ws;
    unsigned short* W1hi = (unsigned short*)(ws);                  // 256KB
    unsigned short* W1lo = (unsigned short*)(ws + 262144);         // 256KB
    unsigned short* Wohi = (unsigned short*)(ws + 524288);         // 128KB
    unsigned short* Wolo = (unsigned short*)(ws + 655360);         // 128KB
    // A panels (27.26MB each); atth/attl alias them (dead after gemm1)
    unsigned short* Gv   = (unsigned short*)(ws + 1048576);
    unsigned short* Gq   = (unsigned short*)(ws + 1048576 + 27262976);
    unsigned short* atth = Gv;
    unsigned short* attl = Gq;
    unsigned short* VPb  = (unsigned short*)(ws + 1048576 + 2 * 27262976);          // 27.23MB
    float*          LB   = (float*)(ws + 1048576 + 2 * 27262976 + 27226112);        // 54.45MB

    convert_A<<<dim3(RPAD / 64), dim3(256), 0, stream>>>(v0, v1, v2, v3,
                                                         p0, p1, p2, p3, Gv, Gq);
    pack_weights<<<dim3(96), dim3(256), 0, stream>>>(Wv, Wattn, Wbox, Wo,
                                                     W1hi, W1lo, Wohi, Wolo);

    gemm1_mfma<<<dim3(4, RPAD / 128), dim3(256), 0, stream>>>(
        Gv, Gq, W1hi, W1lo, bv, battn, bbox, VPb, LB);

    sampler_kernel<<<dim3((BTOT * NH) / 16), dim3(256), 0, stream>>>(VPb, LB, atth, attl);

    gemm2_mfma<<<dim3(2, (BTOT + 127) / 128), dim3(256), 0, stream>>>(
        atth, attl, Wohi, Wolo, bo, out);
}

// Round 8
// 237.434 us; speedup vs baseline: 4.3657x; 1.0339x over previous
//
#include <hip/hip_runtime.h>
#include <cstdint>
#include <cmath>

#define D_MODEL 256
#define NH 8
#define NLVL 4
#define LTOT 13294
#define BATCH 4
#define BTOT (BATCH * LTOT)   // 53176
#define RPAD 53248             // 416 * 128 padded rows

typedef __attribute__((ext_vector_type(8))) short bf8;
typedef __attribute__((ext_vector_type(4))) float f4;
typedef __attribute__((ext_vector_type(2))) float f2;

__device__ __forceinline__ unsigned short f2bf(float x) {
    unsigned u = __float_as_uint(x);
    u += 0x7fffu + ((u >> 16) & 1u);      // round-to-nearest-even
    return (unsigned short)(u >> 16);
}
__device__ __forceinline__ float bf2f(unsigned short h) {
    return __uint_as_float(((unsigned)h) << 16);
}
// unpack dword of 2 bf16 -> f2 {lo, hi}
__device__ __forceinline__ f2 up2(unsigned u) {
    return (f2){__uint_as_float(u << 16), __uint_as_float(u & 0xffff0000u)};
}
// chunk-slot swizzle: slot s of row i holds k-octet s ^ ((i>>1)&3)
__device__ __forceinline__ int swzf(int i, int s) { return s ^ ((i >> 1) & 3); }

// levels: (100,100),(50,50),(25,25),(13,13); offsets 0,10000,12500,13125
__device__ __forceinline__ void level_of(int l, int& lv, int& hw, int& Wl, int& HWl, int& loff) {
    if (l < 10000)      { lv = 0; loff = 0;     Wl = 100; HWl = 10000; }
    else if (l < 12500) { lv = 1; loff = 10000; Wl = 50;  HWl = 2500;  }
    else if (l < 13125) { lv = 2; loff = 12500; Wl = 25;  HWl = 625;   }
    else                { lv = 3; loff = 13125; Wl = 13;  HWl = 169;   }
    hw = l - loff;
}

// ---------------------------------------------------------------- pack weights
__global__ __launch_bounds__(256) void pack_weights(
    const float* __restrict__ Wv, const float* __restrict__ Wattn,
    const float* __restrict__ Wbox, const float* __restrict__ Wo,
    unsigned short* __restrict__ W1hi, unsigned short* __restrict__ W1lo,
    unsigned short* __restrict__ Wohi, unsigned short* __restrict__ Wolo) {
    int tid = blockIdx.x * 256 + threadIdx.x;
    const float* src;
    unsigned short *dh, *dl;
    int nb, kb, j, s;
    if (tid < 16384) {                       // GEMM1 B: 4 nb x 8 kb x 128 j x 4 s
        nb = tid >> 12; kb = (tid >> 9) & 7; j = (tid >> 2) & 127; s = tid & 3;
        int f = nb * 128 + j, c0 = kb * 32 + s * 8;
        if (f < 256)      src = Wv + (size_t)f * 256 + c0;
        else if (f < 384) src = Wattn + (size_t)(f - 256) * 256 + c0;
        else              src = Wbox + (size_t)(f - 384) * 256 + c0;
        dh = W1hi; dl = W1lo;
    } else if (tid < 24576) {                // GEMM2 B: 2 nb x 8 kb x 128 j x 4 s
        int t2 = tid - 16384;
        nb = t2 >> 12; kb = (t2 >> 9) & 7; j = (t2 >> 2) & 127; s = t2 & 3;
        int f = nb * 128 + j, c0 = kb * 32 + s * 8;
        src = Wo + (size_t)f * 256 + c0;
        dh = Wohi; dl = Wolo;
    } else return;
    int base = (((nb * 8 + kb) * 128 + j) * 4 + swzf(j, s)) * 8;
    #pragma unroll
    for (int e = 0; e < 8; ++e) {
        float x = src[e];
        unsigned short h = f2bf(x);
        dh[base + e] = h;
        dl[base + e] = f2bf(x - bf2f(h));
    }
}

// ---------------------------------------------------------------- convert A
__global__ __launch_bounds__(256) void convert_A(
    const float* __restrict__ v0, const float* __restrict__ v1,
    const float* __restrict__ v2, const float* __restrict__ v3,
    const float* __restrict__ p0, const float* __restrict__ p1,
    const float* __restrict__ p2, const float* __restrict__ p3,
    unsigned short* __restrict__ Gv, unsigned short* __restrict__ Gq) {
    __shared__ unsigned short HV[64][130];
    __shared__ unsigned short HQ[64][130];
    int t = threadIdx.x;
    int w = t >> 6, lane = t & 63;
    int r0 = blockIdx.x * 64;

    int r = r0 + lane; if (r >= BTOT) r = BTOT - 1;
    int b = r / LTOT, l = r % LTOT;
    int lv, hw, Wl, HWl, loff;
    level_of(l, lv, hw, Wl, HWl, loff);
    const float *vb, *pb;
    switch (lv) { case 0: vb = v0; pb = p0; break; case 1: vb = v1; pb = p1; break;
                  case 2: vb = v2; pb = p2; break; default: vb = v3; pb = p3; break; }
    size_t base = (size_t)b * D_MODEL * (size_t)HWl + (size_t)hw;
    vb += base; pb += base;

    int kb2 = (lane >> 2) & 3, slot = lane & 3;
    for (int h = 0; h < 2; ++h) {
        #pragma unroll 4
        for (int i = 0; i < 32; ++i) {
            int cl = i * 4 + w;
            int c = h * 128 + cl;
            float av = vb[(size_t)c * HWl];
            float aq = av + pb[(size_t)c * HWl];
            HV[lane][cl] = f2bf(av);
            HQ[lane][cl] = f2bf(aq);
        }
        __syncthreads();
        #pragma unroll
        for (int j = 0; j < 8; ++j) {
            int plane = j >> 2;
            int rl = (j & 3) * 16 + w * 4 + (lane >> 4);
            int oct = slot ^ ((rl >> 1) & 3);
            const unsigned* s32 = (const unsigned*)(plane ? &HQ[rl][kb2 * 32 + oct * 8]
                                                          : &HV[rl][kb2 * 32 + oct * 8]);
            uint4 vst = make_uint4(s32[0], s32[1], s32[2], s32[3]);
            unsigned short* dst = (plane ? Gq : Gv)
                + (size_t)(r0 + rl) * 256 + (h * 4 + kb2) * 32 + slot * 8;
            *(uint4*)dst = vst;
        }
        __syncthreads();
    }
}

// ---------------------------------------------------------------- GEMM1 (MFMA)
// Double-buffered: 1 barrier/K-step, prefetch tile k+1 during compute of k.
__global__ __launch_bounds__(256) void gemm1_mfma(
    const unsigned short* __restrict__ Gv, const unsigned short* __restrict__ Gq,
    const unsigned short* __restrict__ W1hi, const unsigned short* __restrict__ W1lo,
    const float* __restrict__ bv, const float* __restrict__ battn, const float* __restrict__ bbox,
    unsigned short* __restrict__ VPb, float* __restrict__ LB) {
    __shared__ __align__(16) unsigned short Ah[2][4096], Bh[2][4096], Bl[2][4096];
    int t = threadIdx.x;
    int nb = blockIdx.x;                 // 0..3
    int r0 = blockIdx.y * 128;
    const unsigned short* Asrc = (nb < 2) ? Gv : Gq;
    int w = t >> 6, lane = t & 63;
    int wr = w >> 1, wc = w & 1;
    int row_l = lane & 15, oct = lane >> 4;

    const unsigned short* Bbh = W1hi + (size_t)nb * 32768;
    const unsigned short* Bbl = W1lo + (size_t)nb * 32768;

    f4 acc[4][4];
    #pragma unroll
    for (int i = 0; i < 4; ++i)
        #pragma unroll
        for (int j = 0; j < 4; ++j) acc[i][j] = (f4){0.f, 0.f, 0.f, 0.f};

    int c0 = w * 64 + lane, c1 = c0 + 256;
    const unsigned short* a0b = Asrc + (size_t)(r0 + (c0 >> 2)) * 256 + (c0 & 3) * 8;
    const unsigned short* a1b = Asrc + (size_t)(r0 + (c1 >> 2)) * 256 + (c1 & 3) * 8;

#define G1_STAGE(bb, kb)                                                            \
    {                                                                               \
        __builtin_amdgcn_global_load_lds(a0b + (kb) * 32, &Ah[bb][w * 512], 16, 0, 0);        \
        __builtin_amdgcn_global_load_lds(a1b + (kb) * 32, &Ah[bb][2048 + w * 512], 16, 0, 0); \
        __builtin_amdgcn_global_load_lds(Bbh + (kb) * 4096 + c0 * 8, &Bh[bb][w * 512], 16, 0, 0);        \
        __builtin_amdgcn_global_load_lds(Bbh + (kb) * 4096 + c1 * 8, &Bh[bb][2048 + w * 512], 16, 0, 0); \
        __builtin_amdgcn_global_load_lds(Bbl + (kb) * 4096 + c0 * 8, &Bl[bb][w * 512], 16, 0, 0);        \
        __builtin_amdgcn_global_load_lds(Bbl + (kb) * 4096 + c1 * 8, &Bl[bb][2048 + w * 512], 16, 0, 0); \
    }

    G1_STAGE(0, 0);
    for (int kb = 0; kb < 8; ++kb) {
        __syncthreads();                       // drains prefetch; buf kb ready
        if (kb < 7) G1_STAGE((kb + 1) & 1, kb + 1);
        int bb = kb & 1;
        bf8 a[4], bh[4], bl[4];
        #pragma unroll
        for (int x = 0; x < 4; ++x) {
            int ri = wr * 64 + x * 16 + row_l;
            int ci = wc * 64 + x * 16 + row_l;
            a[x]  = *(const bf8*)(&Ah[bb][ri * 32 + swzf(ri, oct) * 8]);
            bh[x] = *(const bf8*)(&Bh[bb][ci * 32 + swzf(ci, oct) * 8]);
            bl[x] = *(const bf8*)(&Bl[bb][ci * 32 + swzf(ci, oct) * 8]);
        }
        #pragma unroll
        for (int mi = 0; mi < 4; ++mi)
            #pragma unroll
            for (int ni = 0; ni < 4; ++ni) {
                f4 c = acc[mi][ni];
                c = __builtin_amdgcn_mfma_f32_16x16x32_bf16(a[mi], bh[ni], c, 0, 0, 0);
                c = __builtin_amdgcn_mfma_f32_16x16x32_bf16(a[mi], bl[ni], c, 0, 0, 0);
                acc[mi][ni] = c;
            }
    }
    #pragma unroll
    for (int ni = 0; ni < 4; ++ni) {
        int col = wc * 64 + ni * 16 + row_l;
        float bias;
        if (nb == 0) bias = bv[col];
        else if (nb == 1) bias = bv[128 + col];
        else if (nb == 2) bias = battn[col];
        else bias = bbox[col];
        #pragma unroll
        for (int mi = 0; mi < 4; ++mi) {
            #pragma unroll
            for (int v = 0; v < 4; ++v) {
                int rr = r0 + wr * 64 + mi * 16 + oct * 4 + v;
                if (rr < BTOT) {
                    float val = acc[mi][ni][v] + bias;
                    if (nb < 2) VPb[(size_t)rr * 256 + nb * 128 + col] = f2bf(val);
                    else        LB[(size_t)rr * 256 + (nb - 2) * 128 + col] = val;
                }
            }
        }
    }
}

// ---------------------------------------------------------------- sampler v6
// Block = 256 threads = 64 groups. Phase 1: 4 passes of 16 grp x 16 pt ->
// LDS [64][132]: per pt {w00,w01,w10,w11, i00,i01,i10,i11} (byte offsets).
// Phase 2: 4 lanes/group, 8 channels/lane via dwordx4 gathers, packed f32 fma.
__global__ __launch_bounds__(256) void sampler_kernel(const unsigned short* __restrict__ VPb,
                                                      const float* __restrict__ LB,
                                                      unsigned short* __restrict__ att_hi,
                                                      unsigned short* __restrict__ att_lo) {
    __shared__ float sw[64][132];    // 33.8 KB
    const int Ws2[4]   = {100, 50, 25, 13};
    const int offs2[4] = {0, 10000, 12500, 13125};
    int t = threadIdx.x;
    int blk = blockIdx.x;            // BTOT*NH/64 = 6647 blocks

    #pragma unroll
    for (int pass = 0; pass < 4; ++pass) {
        int g = (t >> 4) + pass * 16;
        int p = t & 15;
        int grp = blk * 64 + g;
        int m = grp & 7;
        int r = grp >> 3;
        int l = r % LTOT;
        int rb0 = r - l;

        int lv, hw, Wl, HWl, loff;
        level_of(l, lv, hw, Wl, HWl, loff);
        int x, y;
        switch (lv) {
            case 0:  y = hw / 100; x = hw - y * 100; break;
            case 1:  y = hw / 50;  x = hw - y * 50;  break;
            case 2:  y = hw / 25;  x = hw - y * 25;  break;
            default: y = hw / 13;  x = hw - y * 13;  break;
        }
        float denom = (float)((double)Wl + 1e-6);
        float cx = ((float)x + 0.5f) / denom;
        float cy = ((float)y + 0.5f) / denom;
        float rsw = 4.0f / (float)Wl;

        const float* Lrow = LB + (size_t)r * 256;
        float lg = Lrow[m * 16 + p];
        float mx = lg;
        #pragma unroll
        for (int off = 8; off >= 1; off >>= 1)
            mx = fmaxf(mx, __shfl_xor(mx, off, 16));
        float e = __expf(lg - mx);
        float ssum = e;
        #pragma unroll
        for (int off = 8; off >= 1; off >>= 1)
            ssum += __shfl_xor(ssum, off, 16);
        float aw = e / ssum;

        int lp = p >> 2, pp = p & 3;
        int W2 = Ws2[lp];
        float fW2 = (float)W2;
        float o0 = Lrow[128 + m * 16 + lp * 4 + 0];
        float o1 = Lrow[128 + m * 16 + lp * 4 + 1];
        float o2 = Lrow[128 + m * 16 + lp * 4 + 2];
        float o3 = Lrow[128 + m * 16 + lp * 4 + 3];
        float bcx = cx + o0 * 0.125f * rsw;
        float bcy = cy + o1 * 0.125f * rsw;
        float bsx = fmaxf(fmaf(o2 * 0.125f, rsw, rsw), 0.f);
        float bsy = fmaxf(fmaf(o3 * 0.125f, rsw, rsw), 0.f);
        float kx = (pp & 1)  ? 0.25f : -0.25f;
        float ky = (pp >> 1) ? 0.25f : -0.25f;
        float xs = fmaf(bcx + kx * bsx, fW2, -0.5f);
        float ys = fmaf(bcy + ky * bsy, fW2, -0.5f);
        float x0f = floorf(xs), y0f = floorf(ys);
        float lx = xs - x0f, ly = ys - y0f;
        int x0 = (int)x0f, y0 = (int)y0f;
        int x1 = x0 + 1, y1 = y0 + 1;
        bool vx0 = (x0 >= 0) & (x0 < W2), vx1 = (x1 >= 0) & (x1 < W2);
        bool vy0 = (y0 >= 0) & (y0 < W2), vy1 = (y1 >= 0) & (y1 < W2);
        int x0c = min(max(x0, 0), W2 - 1), x1c = min(max(x1, 0), W2 - 1);
        int y0c = min(max(y0, 0), W2 - 1), y1c = min(max(y1, 0), W2 - 1);
        float w00 = (vx0 & vy0) ? aw * (1.f - lx) * (1.f - ly) : 0.f;
        float w01 = (vx1 & vy0) ? aw * lx * (1.f - ly) : 0.f;
        float w10 = (vx0 & vy1) ? aw * (1.f - lx) * ly : 0.f;
        float w11 = (vx1 & vy1) ? aw * lx * ly : 0.f;
        int rowb = rb0 + offs2[lp];
        int col  = m * 32;
        int i00 = ((rowb + y0c * W2 + x0c) * 256 + col) * 2;   // BYTE offsets
        int i01 = ((rowb + y0c * W2 + x1c) * 256 + col) * 2;
        int i10 = ((rowb + y1c * W2 + x0c) * 256 + col) * 2;
        int i11 = ((rowb + y1c * W2 + x1c) * 256 + col) * 2;
        float* dst = &sw[g][p * 8];
        *(float4*)dst       = (float4){w00, w01, w10, w11};
        *(float4*)(dst + 4) = (float4){__int_as_float(i00), __int_as_float(i01),
                                       __int_as_float(i10), __int_as_float(i11)};
    }
    __syncthreads();

    int g = t >> 2, lane4 = t & 3;
    unsigned dby = (unsigned)lane4 * 16u;          // 8 channels x 2B
    const char* Vb = (const char*)VPb;
    f2 a01 = {0.f, 0.f}, a23 = {0.f, 0.f}, a45 = {0.f, 0.f}, a67 = {0.f, 0.f};
    #pragma unroll
    for (int p = 0; p < 16; ++p) {
        const float* sp = &sw[g][p * 8];
        float4 wv = *(const float4*)sp;
        float4 fi = *(const float4*)(sp + 4);
        uint4 u00 = *(const uint4*)(Vb + (size_t)(__float_as_uint(fi.x) + dby));
        uint4 u01 = *(const uint4*)(Vb + (size_t)(__float_as_uint(fi.y) + dby));
        uint4 u10 = *(const uint4*)(Vb + (size_t)(__float_as_uint(fi.z) + dby));
        uint4 u11 = *(const uint4*)(Vb + (size_t)(__float_as_uint(fi.w) + dby));
        f2 w0 = {wv.x, wv.x}, w1 = {wv.y, wv.y}, w2 = {wv.z, wv.z}, w3 = {wv.w, wv.w};
        a01 = __builtin_elementwise_fma(w0, up2(u00.x), a01);
        a23 = __builtin_elementwise_fma(w0, up2(u00.y), a23);
        a45 = __builtin_elementwise_fma(w0, up2(u00.z), a45);
        a67 = __builtin_elementwise_fma(w0, up2(u00.w), a67);
        a01 = __builtin_elementwise_fma(w1, up2(u01.x), a01);
        a23 = __builtin_elementwise_fma(w1, up2(u01.y), a23);
        a45 = __builtin_elementwise_fma(w1, up2(u01.z), a45);
        a67 = __builtin_elementwise_fma(w1, up2(u01.w), a67);
        a01 = __builtin_elementwise_fma(w2, up2(u10.x), a01);
        a23 = __builtin_elementwise_fma(w2, up2(u10.y), a23);
        a45 = __builtin_elementwise_fma(w2, up2(u10.z), a45);
        a67 = __builtin_elementwise_fma(w2, up2(u10.w), a67);
        a01 = __builtin_elementwise_fma(w3, up2(u11.x), a01);
        a23 = __builtin_elementwise_fma(w3, up2(u11.y), a23);
        a45 = __builtin_elementwise_fma(w3, up2(u11.z), a45);
        a67 = __builtin_elementwise_fma(w3, up2(u11.w), a67);
    }
    int grp = blk * 64 + g;
    int m2 = grp & 7, r2 = grp >> 3;
    // 8 channels d0..d0+7 = one full octet; baked swizzle for GEMM2 A staging
    int slot = lane4 ^ ((r2 >> 1) & 3);
    size_t base = (size_t)r2 * 256 + m2 * 32 + slot * 8;
    float av[8] = {a01.x, a01.y, a23.x, a23.y, a45.x, a45.y, a67.x, a67.y};
    unsigned hp[4], lp4[4];
    #pragma unroll
    for (int q = 0; q < 4; ++q) {
        unsigned short h0 = f2bf(av[q * 2]), h1 = f2bf(av[q * 2 + 1]);
        unsigned short l0 = f2bf(av[q * 2] - bf2f(h0)), l1 = f2bf(av[q * 2 + 1] - bf2f(h1));
        hp[q]  = ((unsigned)h1 << 16) | h0;
        lp4[q] = ((unsigned)l1 << 16) | l0;
    }
    *(uint4*)&att_hi[base] = make_uint4(hp[0], hp[1], hp[2], hp[3]);
    *(uint4*)&att_lo[base] = make_uint4(lp4[0], lp4[1], lp4[2], lp4[3]);
}

// ---------------------------------------------------------------- GEMM2 (MFMA)
// Double-buffered, 1 barrier/K-step.
__global__ __launch_bounds__(256) void gemm2_mfma(
    const unsigned short* __restrict__ Ahi_g, const unsigned short* __restrict__ Alo_g,
    const unsigned short* __restrict__ Wohi, const unsigned short* __restrict__ Wolo,
    const float* __restrict__ bo, float* __restrict__ out) {
    __shared__ __align__(16) unsigned short Ah[2][4096], Al[2][4096], Bh[2][4096], Bl[2][4096];
    int t = threadIdx.x;
    int nb = blockIdx.x;                 // 0..1
    int r0 = blockIdx.y * 128;
    int w = t >> 6, lane = t & 63;
    int wr = w >> 1, wc = w & 1;
    int row_l = lane & 15, oct = lane >> 4;

    const unsigned short* Bbh = Wohi + (size_t)nb * 32768;
    const unsigned short* Bbl = Wolo + (size_t)nb * 32768;

    f4 acc[4][4];
    #pragma unroll
    for (int i = 0; i < 4; ++i)
        #pragma unroll
        for (int j = 0; j < 4; ++j) acc[i][j] = (f4){0.f, 0.f, 0.f, 0.f};

    int c0 = w * 64 + lane, c1 = c0 + 256;
    int ra0 = r0 + (c0 >> 2); if (ra0 >= BTOT) ra0 = BTOT - 1;
    int ra1 = r0 + (c1 >> 2); if (ra1 >= BTOT) ra1 = BTOT - 1;
    const unsigned short* ah0 = Ahi_g + (size_t)ra0 * 256 + (c0 & 3) * 8;
    const unsigned short* ah1 = Ahi_g + (size_t)ra1 * 256 + (c1 & 3) * 8;
    const unsigned short* al0 = Alo_g + (size_t)ra0 * 256 + (c0 & 3) * 8;
    const unsigned short* al1 = Alo_g + (size_t)ra1 * 256 + (c1 & 3) * 8;

#define G2_STAGE(bb, kb)                                                            \
    {                                                                               \
        __builtin_amdgcn_global_load_lds(ah0 + (kb) * 32, &Ah[bb][w * 512], 16, 0, 0);        \
        __builtin_amdgcn_global_load_lds(ah1 + (kb) * 32, &Ah[bb][2048 + w * 512], 16, 0, 0); \
        __builtin_amdgcn_global_load_lds(al0 + (kb) * 32, &Al[bb][w * 512], 16, 0, 0);        \
        __builtin_amdgcn_global_load_lds(al1 + (kb) * 32, &Al[bb][2048 + w * 512], 16, 0, 0); \
        __builtin_amdgcn_global_load_lds(Bbh + (kb) * 4096 + c0 * 8, &Bh[bb][w * 512], 16, 0, 0);        \
        __builtin_amdgcn_global_load_lds(Bbh + (kb) * 4096 + c1 * 8, &Bh[bb][2048 + w * 512], 16, 0, 0); \
        __builtin_amdgcn_global_load_lds(Bbl + (kb) * 4096 + c0 * 8, &Bl[bb][w * 512], 16, 0, 0);        \
        __builtin_amdgcn_global_load_lds(Bbl + (kb) * 4096 + c1 * 8, &Bl[bb][2048 + w * 512], 16, 0, 0); \
    }

    G2_STAGE(0, 0);
    for (int kb = 0; kb < 8; ++kb) {
        __syncthreads();
        if (kb < 7) G2_STAGE((kb + 1) & 1, kb + 1);
        int bb = kb & 1;
        bf8 ah[4], al[4], bh[4], bl[4];
        #pragma unroll
        for (int x = 0; x < 4; ++x) {
            int ri = wr * 64 + x * 16 + row_l;
            int ci = wc * 64 + x * 16 + row_l;
            ah[x] = *(const bf8*)(&Ah[bb][ri * 32 + swzf(ri, oct) * 8]);
            al[x] = *(const bf8*)(&Al[bb][ri * 32 + swzf(ri, oct) * 8]);
            bh[x] = *(const bf8*)(&Bh[bb][ci * 32 + swzf(ci, oct) * 8]);
            bl[x] = *(const bf8*)(&Bl[bb][ci * 32 + swzf(ci, oct) * 8]);
        }
        #pragma unroll
        for (int mi = 0; mi < 4; ++mi)
            #pragma unroll
            for (int ni = 0; ni < 4; ++ni) {
                f4 c = acc[mi][ni];
                c = __builtin_amdgcn_mfma_f32_16x16x32_bf16(ah[mi], bh[ni], c, 0, 0, 0);
                c = __builtin_amdgcn_mfma_f32_16x16x32_bf16(ah[mi], bl[ni], c, 0, 0, 0);
                c = __builtin_amdgcn_mfma_f32_16x16x32_bf16(al[mi], bh[ni], c, 0, 0, 0);
                acc[mi][ni] = c;
            }
    }
    #pragma unroll
    for (int ni = 0; ni < 4; ++ni) {
        int col = wc * 64 + ni * 16 + row_l;
        float bias = bo[nb * 128 + col];
        #pragma unroll
        for (int mi = 0; mi < 4; ++mi) {
            #pragma unroll
            for (int v = 0; v < 4; ++v) {
                int rr = r0 + wr * 64 + mi * 16 + oct * 4 + v;
                if (rr < BTOT)
                    out[(size_t)rr * 256 + nb * 128 + col] = acc[mi][ni][v] + bias;
            }
        }
    }
}

// ---------------------------------------------------------------- launch
extern "C" void kernel_launch(void* const* d_in, const int* in_sizes, int n_in,
                              void* d_out, int out_size, void* d_ws, size_t ws_size,
                              hipStream_t stream) {
    const float* v0 = (const float*)d_in[0];
    const float* p0 = (const float*)d_in[1];
    const float* v1 = (const float*)d_in[2];
    const float* p1 = (const float*)d_in[3];
    const float* v2 = (const float*)d_in[4];
    const float* p2 = (const float*)d_in[5];
    const float* v3 = (const float*)d_in[6];
    const float* p3 = (const float*)d_in[7];
    const float* Wv    = (const float*)d_in[8];
    const float* bv    = (const float*)d_in[9];
    const float* Wo    = (const float*)d_in[10];
    const float* bo    = (const float*)d_in[11];
    const float* Wbox  = (const float*)d_in[12];
    const float* bbox  = (const float*)d_in[13];
    const float* Wattn = (const float*)d_in[14];
    const float* battn = (const float*)d_in[15];
    float* out = (float*)d_out;

    char* ws = (char*)d_ws;
    unsigned short* W1hi = (unsigned short*)(ws);                  // 256KB
    unsigned short* W1lo = (unsigned short*)(ws + 262144);         // 256KB
    unsigned short* Wohi = (unsigned short*)(ws + 524288);         // 128KB
    unsigned short* Wolo = (unsigned short*)(ws + 655360);         // 128KB
    // A panels (27.26MB each); atth/attl alias them (dead after gemm1)
    unsigned short* Gv   = (unsigned short*)(ws + 1048576);
    unsigned short* Gq   = (unsigned short*)(ws + 1048576 + 27262976);
    unsigned short* atth = Gv;
    unsigned short* attl = Gq;
    unsigned short* VPb  = (unsigned short*)(ws + 1048576 + 2 * 27262976);          // 27.23MB
    float*          LB   = (float*)(ws + 1048576 + 2 * 27262976 + 27226112);        // 54.45MB

    convert_A<<<dim3(RPAD / 64), dim3(256), 0, stream>>>(v0, v1, v2, v3,
                                                         p0, p1, p2, p3, Gv, Gq);
    pack_weights<<<dim3(96), dim3(256), 0, stream>>>(Wv, Wattn, Wbox, Wo,
                                                     W1hi, W1lo, Wohi, Wolo);

    gemm1_mfma<<<dim3(4, RPAD / 128), dim3(256), 0, stream>>>(
        Gv, Gq, W1hi, W1lo, bv, battn, bbox, VPb, LB);

    sampler_kernel<<<dim3((BTOT * NH) / 64), dim3(256), 0, stream>>>(VPb, LB, atth, attl);

    gemm2_mfma<<<dim3(2, (BTOT + 127) / 128), dim3(256), 0, stream>>>(
        atth, attl, Wohi, Wolo, bo, out);
}